// Round 1
// baseline (1253.913 us; speedup 1.0000x reference)
//
#include <hip/hip_runtime.h>

// GNN: 2-layer bipartite GraphConv + link decoder. All fp32.
// Pipeline per call (deterministic work; CSR fill slot order is atomic and may
// permute fp add order run-to-run — rounding noise ~1e-6 << 1.3e-3 threshold):
//   counts -> scan -> CSR fill -> per-dst-wave mean-aggregate ->
//   fused (rel|root) K=256 GEMM per conv -> fused decoder MLP.

#define D 128

// ---------------- utility kernels ----------------

__global__ void count_k(const int* __restrict__ dst, int* __restrict__ cnt, int E) {
  int i = blockIdx.x * 256 + threadIdx.x;
  if (i < E) atomicAdd(&cnt[dst[i]], 1);
}

__global__ void scan_chunk_k(const int* __restrict__ in, int* __restrict__ out,
                             int* __restrict__ sums, int n) {
  __shared__ int lds[256];
  int t = threadIdx.x;
  int base = blockIdx.x * 1024 + t * 4;
  int v0 = (base + 0 < n) ? in[base + 0] : 0;
  int v1 = (base + 1 < n) ? in[base + 1] : 0;
  int v2 = (base + 2 < n) ? in[base + 2] : 0;
  int v3 = (base + 3 < n) ? in[base + 3] : 0;
  int s = v0 + v1 + v2 + v3;
  lds[t] = s;
  __syncthreads();
  for (int off = 1; off < 256; off <<= 1) {
    int x = (t >= off) ? lds[t - off] : 0;
    __syncthreads();
    lds[t] += x;
    __syncthreads();
  }
  int excl = lds[t] - s;
  if (t == 255) sums[blockIdx.x] = lds[255];
  if (base + 0 < n) out[base + 0] = excl; excl += v0;
  if (base + 1 < n) out[base + 1] = excl; excl += v1;
  if (base + 2 < n) out[base + 2] = excl; excl += v2;
  if (base + 3 < n) out[base + 3] = excl;
}

__global__ void scan_tops_k(int* __restrict__ sums, int nb) {
  if (threadIdx.x == 0 && blockIdx.x == 0) {
    int run = 0;
    for (int i = 0; i < nb; ++i) { int x = sums[i]; sums[i] = run; run += x; }
  }
}

__global__ void scan_add_k(int* __restrict__ out, const int* __restrict__ sums, int n) {
  int i = blockIdx.x * 256 + threadIdx.x;
  if (i < n) out[i] += sums[i >> 10];
}

__global__ void fill_k(const int* __restrict__ src, const int* __restrict__ dst,
                       const int* __restrict__ off, int* __restrict__ cur,
                       int* __restrict__ csr, int E) {
  int i = blockIdx.x * 256 + threadIdx.x;
  if (i < E) {
    int d = dst[i];
    int p = off[d] + atomicAdd(&cur[d], 1);
    csr[p] = src[i];
  }
}

__global__ void inv_k(const int* __restrict__ cnt, float* __restrict__ inv, int n) {
  int i = blockIdx.x * 256 + threadIdx.x;
  if (i < n) inv[i] = 1.0f / fmaxf((float)cnt[i], 1.0f);
}

// out[k*J + j] = in[j*K + k]
__global__ void trans_k(const float* __restrict__ in, float* __restrict__ out, int J, int K) {
  int id = blockIdx.x * 256 + threadIdx.x;
  if (id < J * K) {
    int j = id % J;
    int k = id / J;
    out[(size_t)k * J + j] = in[(size_t)j * K + k];
  }
}

// ---------------- aggregation: one wave per destination node ----------------

__global__ __launch_bounds__(256) void agg_mean_k(
    const float* __restrict__ xsrc, const int* __restrict__ csr,
    const int* __restrict__ off, const int* __restrict__ cnt,
    const float* __restrict__ inv, float* __restrict__ mean, int ndst) {
  int wid = blockIdx.x * 4 + (threadIdx.x >> 6);
  int lane = threadIdx.x & 63;
  if (wid >= ndst) return;
  int o = off[wid];
  int deg = cnt[wid];
  float ax = 0.f, ay = 0.f;
  const float2* xs = (const float2*)xsrc;
  int sNext = (deg > 0) ? csr[o] : 0;
  for (int i = 0; i < deg; ++i) {
    int s = sNext;
    if (i + 1 < deg) sNext = csr[o + i + 1];   // prefetch next index
    float2 v = xs[(size_t)s * 64 + lane];
    ax += v.x; ay += v.y;
  }
  float iv = inv[wid];
  float2 r; r.x = ax * iv; r.y = ay * iv;
  ((float2*)mean)[(size_t)wid * 64 + lane] = r;
}

// ---------------- fused GraphConv GEMM: out = [mean|x] @ WT + b ----------------
// WT is [256][128]: rows 0..127 = W_rel^T, rows 128..255 = W_root^T.
// 64 rows x 128 cols per block, 256 threads, acc[4][8] per thread.

__global__ __launch_bounds__(256) void gemm_conv_k(
    const float* __restrict__ A1, const float* __restrict__ A2,
    const float* __restrict__ WT, const float* __restrict__ bias,
    float* __restrict__ out, int n, int relu) {
  __shared__ float At[32][72];    // [k][row] transposed A chunk
  __shared__ float Wc[32][132];   // [k][col] weight chunk
  const int t = threadIdx.x;
  const int tx = t & 15, ty = t >> 4;
  const int c0 = tx * 8, r0 = ty * 4;
  const int row0 = blockIdx.x * 64;

  float acc[4][8];
  {
    float4 b0 = *(const float4*)&bias[c0];
    float4 b1 = *(const float4*)&bias[c0 + 4];
    float bv[8] = {b0.x, b0.y, b0.z, b0.w, b1.x, b1.y, b1.z, b1.w};
#pragma unroll
    for (int rr = 0; rr < 4; ++rr)
#pragma unroll
      for (int cc = 0; cc < 8; ++cc) acc[rr][cc] = bv[cc];
  }

  const int ar = t >> 2;          // 0..63 staging row
  const int ak = (t & 3) * 8;     // k offset within chunk
  const int arow = row0 + ar;

  for (int ch = 0; ch < 8; ++ch) {
    const int k0 = ch * 32;
    const float* __restrict__ Asrc = (ch < 4) ? A1 : A2;
    const int kb = k0 & 127;
    __syncthreads();
#pragma unroll
    for (int i = 0; i < 4; ++i) {
      int flat = t + i * 256;          // float4 units of the 32x128 chunk
      int kk = flat >> 5, cq = flat & 31;
      *(float4*)&Wc[kk][cq * 4] = *(const float4*)&WT[(size_t)(k0 + kk) * D + cq * 4];
    }
    {
      float4 a0 = {0, 0, 0, 0}, a1 = {0, 0, 0, 0};
      if (arow < n) {
        a0 = *(const float4*)&Asrc[(size_t)arow * D + kb + ak];
        a1 = *(const float4*)&Asrc[(size_t)arow * D + kb + ak + 4];
      }
      At[ak + 0][ar] = a0.x; At[ak + 1][ar] = a0.y; At[ak + 2][ar] = a0.z; At[ak + 3][ar] = a0.w;
      At[ak + 4][ar] = a1.x; At[ak + 5][ar] = a1.y; At[ak + 6][ar] = a1.z; At[ak + 7][ar] = a1.w;
    }
    __syncthreads();
#pragma unroll 8
    for (int kk = 0; kk < 32; ++kk) {
      float4 a4 = *(const float4*)&At[kk][r0];
      float4 w0 = *(const float4*)&Wc[kk][c0];
      float4 w1 = *(const float4*)&Wc[kk][c0 + 4];
      float av[4] = {a4.x, a4.y, a4.z, a4.w};
      float wv[8] = {w0.x, w0.y, w0.z, w0.w, w1.x, w1.y, w1.z, w1.w};
#pragma unroll
      for (int rr = 0; rr < 4; ++rr)
#pragma unroll
        for (int cc = 0; cc < 8; ++cc)
          acc[rr][cc] = fmaf(av[rr], wv[cc], acc[rr][cc]);
    }
  }

#pragma unroll
  for (int rr = 0; rr < 4; ++rr) {
    int row = row0 + r0 + rr;
    if (row < n) {
      float o[8];
#pragma unroll
      for (int cc = 0; cc < 8; ++cc) {
        float v = acc[rr][cc];
        o[cc] = relu ? fmaxf(v, 0.f) : v;
      }
      *(float4*)&out[(size_t)row * D + c0]     = make_float4(o[0], o[1], o[2], o[3]);
      *(float4*)&out[(size_t)row * D + c0 + 4] = make_float4(o[4], o[5], o[6], o[7]);
    }
  }
}

// ---------------- fused decoder: e=xv[lv]-xh[lh]; relu(e@W1T+b1); relu(@W2T+b2); @Wp+bp
// 64 rows per block. h1 kept in LDS (pool reused from At/Wc region).

__global__ __launch_bounds__(256) void decoder_k(
    const float* __restrict__ xv, const float* __restrict__ xh,
    const int* __restrict__ lv, const int* __restrict__ lh,
    const float* __restrict__ W1T, const float* __restrict__ b1,
    const float* __restrict__ W2T, const float* __restrict__ b2,
    const float* __restrict__ Wp, const float* __restrict__ bp,
    float* __restrict__ out, int L) {
  // pool: first used as At(32x72)+Wc(32x132) = 6528 floats, then as h1[64][129] = 8256 floats
  __shared__ __align__(16) float pool[8256];
  __shared__ __align__(16) float W2L[128][36];
  float* At_ = pool;               // [kk*72 + r]
  float* Wc_ = pool + 2304;        // [kk*132 + c]
  float* h1_ = pool;               // [r*129 + k]

  const int t = threadIdx.x;
  const int tx = t & 15, ty = t >> 4;
  const int c0 = tx * 8, r0 = ty * 4;
  const int row0 = blockIdx.x * 64;

  // stage W2T (dense [128][32]) into padded LDS
#pragma unroll
  for (int i = 0; i < 4; ++i) {
    int flat = t + i * 256;          // float4 units, 1024 total
    int k = flat >> 3, q = flat & 7;
    *(float4*)&W2L[k][q * 4] = *(const float4*)&W2T[(size_t)k * 32 + q * 4];
  }

  float acc[4][8];
  {
    float4 b0 = *(const float4*)&b1[c0];
    float4 bb = *(const float4*)&b1[c0 + 4];
    float bv[8] = {b0.x, b0.y, b0.z, b0.w, bb.x, bb.y, bb.z, bb.w};
#pragma unroll
    for (int rr = 0; rr < 4; ++rr)
#pragma unroll
      for (int cc = 0; cc < 8; ++cc) acc[rr][cc] = bv[cc];
  }

  const int ar = t >> 2;
  const int ak = (t & 3) * 8;
  const int arow = row0 + ar;
  int iv = 0, ih = 0;
  const bool valid = (arow < L);
  if (valid) { iv = lv[arow]; ih = lh[arow]; }

  for (int ch = 0; ch < 4; ++ch) {
    const int k0 = ch * 32;
    __syncthreads();
#pragma unroll
    for (int i = 0; i < 4; ++i) {
      int flat = t + i * 256;
      int kk = flat >> 5, cq = flat & 31;
      *(float4*)&Wc_[kk * 132 + cq * 4] = *(const float4*)&W1T[(size_t)(k0 + kk) * D + cq * 4];
    }
    {
      float e[8] = {0, 0, 0, 0, 0, 0, 0, 0};
      if (valid) {
        float4 v0 = *(const float4*)&xv[(size_t)iv * D + k0 + ak];
        float4 v1 = *(const float4*)&xv[(size_t)iv * D + k0 + ak + 4];
        float4 h0 = *(const float4*)&xh[(size_t)ih * D + k0 + ak];
        float4 h1v = *(const float4*)&xh[(size_t)ih * D + k0 + ak + 4];
        e[0] = v0.x - h0.x; e[1] = v0.y - h0.y; e[2] = v0.z - h0.z; e[3] = v0.w - h0.w;
        e[4] = v1.x - h1v.x; e[5] = v1.y - h1v.y; e[6] = v1.z - h1v.z; e[7] = v1.w - h1v.w;
      }
#pragma unroll
      for (int i = 0; i < 8; ++i) At_[(ak + i) * 72 + ar] = e[i];
    }
    __syncthreads();
#pragma unroll 8
    for (int kk = 0; kk < 32; ++kk) {
      float4 a4 = *(const float4*)&At_[kk * 72 + r0];
      float4 w0 = *(const float4*)&Wc_[kk * 132 + c0];
      float4 w1 = *(const float4*)&Wc_[kk * 132 + c0 + 4];
      float av[4] = {a4.x, a4.y, a4.z, a4.w};
      float wv[8] = {w0.x, w0.y, w0.z, w0.w, w1.x, w1.y, w1.z, w1.w};
#pragma unroll
      for (int rr = 0; rr < 4; ++rr)
#pragma unroll
        for (int cc = 0; cc < 8; ++cc)
          acc[rr][cc] = fmaf(av[rr], wv[cc], acc[rr][cc]);
    }
  }

  // relu + write h1 into pool (At/Wc dead after barrier)
  __syncthreads();
#pragma unroll
  for (int rr = 0; rr < 4; ++rr)
#pragma unroll
    for (int cc = 0; cc < 8; ++cc)
      h1_[(r0 + rr) * 129 + c0 + cc] = fmaxf(acc[rr][cc], 0.f);
  __syncthreads();

  // stage 2: h2 = relu(h1 @ W2T + b2), then out = h2 . Wp + bp
  const int r2 = t >> 2;
  const int c2 = (t & 3) * 8;
  float acc2[8];
#pragma unroll
  for (int j = 0; j < 8; ++j) acc2[j] = b2[c2 + j];
  for (int k = 0; k < 128; ++k) {
    float a = h1_[r2 * 129 + k];
    float4 w0 = *(const float4*)&W2L[k][c2];
    float4 w1 = *(const float4*)&W2L[k][c2 + 4];
    acc2[0] = fmaf(a, w0.x, acc2[0]); acc2[1] = fmaf(a, w0.y, acc2[1]);
    acc2[2] = fmaf(a, w0.z, acc2[2]); acc2[3] = fmaf(a, w0.w, acc2[3]);
    acc2[4] = fmaf(a, w1.x, acc2[4]); acc2[5] = fmaf(a, w1.y, acc2[5]);
    acc2[6] = fmaf(a, w1.z, acc2[6]); acc2[7] = fmaf(a, w1.w, acc2[7]);
  }
  float4 wp0 = *(const float4*)&Wp[c2];
  float4 wp1 = *(const float4*)&Wp[c2 + 4];
  float wpv[8] = {wp0.x, wp0.y, wp0.z, wp0.w, wp1.x, wp1.y, wp1.z, wp1.w};
  float p = 0.f;
#pragma unroll
  for (int j = 0; j < 8; ++j) p += fmaxf(acc2[j], 0.f) * wpv[j];
  p += __shfl_xor(p, 1);
  p += __shfl_xor(p, 2);
  int row = row0 + r2;
  if ((t & 3) == 0 && row < L) out[row] = p + bp[0];
}

// ---------------- host launcher ----------------

extern "C" void kernel_launch(void* const* d_in, const int* in_sizes, int n_in,
                              void* d_out, int out_size, void* d_ws, size_t ws_size,
                              hipStream_t stream) {
  const float* x_virus = (const float*)d_in[0];
  const float* x_host  = (const float*)d_in[1];
  const int* src_vh = (const int*)d_in[2];
  const int* dst_vh = (const int*)d_in[3];
  const int* src_hv = (const int*)d_in[4];
  const int* dst_hv = (const int*)d_in[5];
  const int* lbl_v  = (const int*)d_in[6];
  const int* lbl_h  = (const int*)d_in[7];
  const float* Wc_[4][2] = {
      {(const float*)d_in[8],  (const float*)d_in[10]},   // vh layer0: rel, root
      {(const float*)d_in[11], (const float*)d_in[13]},   // hv layer0
      {(const float*)d_in[14], (const float*)d_in[16]},   // vh layer1
      {(const float*)d_in[17], (const float*)d_in[19]},   // hv layer1
  };
  const float* bias_c[4] = {(const float*)d_in[9], (const float*)d_in[12],
                            (const float*)d_in[15], (const float*)d_in[18]};
  const float* W1 = (const float*)d_in[20];
  const float* b1 = (const float*)d_in[21];
  const float* W2 = (const float*)d_in[22];
  const float* b2 = (const float*)d_in[23];
  const float* Wp = (const float*)d_in[24];
  const float* bp = (const float*)d_in[25];

  const int NV = in_sizes[0] / D;
  const int NH = in_sizes[1] / D;
  const int E  = in_sizes[2];
  const int L  = in_sizes[6];

  // ---- workspace carve-up (floats, all 16B aligned) ----
  float* ws = (float*)d_ws;
  size_t o = 0;
  auto falloc = [&](size_t nf) { float* p = ws + o; o += nf; return p; };
  float* xv1   = falloc((size_t)NV * D);
  float* xv2   = falloc((size_t)NV * D);
  float* meanb = falloc((size_t)NV * D);      // shared by host & virus aggregations
  float* xh1   = falloc((size_t)NH * D);
  float* xh2   = falloc((size_t)NH * D);
  float* WT[4];
  for (int c = 0; c < 4; ++c) WT[c] = falloc(256 * D);
  float* W1T = falloc(D * D);
  float* W2T = falloc((size_t)D * 32);
  float* inv_h = falloc(NH);
  float* inv_v = falloc(NV);
  int* ib = (int*)(ws + o);
  size_t io = 0;
  auto ialloc = [&](size_t ni) { int* p = ib + io; io += ni; return p; };
  int* cnt_h = ialloc(NH);
  int* cur_h = ialloc(NH);
  int* cnt_v = ialloc(NV);
  int* cur_v = ialloc(NV);
  int* off_h = ialloc(NH);
  int* off_v = ialloc(NV);
  int* csr_h = ialloc(E);
  int* csr_v = ialloc(E);
  int* sums  = ialloc(128);

  auto cdiv = [](int a, int b) { return (a + b - 1) / b; };

  // zero cnt/cur (contiguous block)
  hipMemsetAsync(cnt_h, 0, (size_t)(2 * NH + 2 * NV) * sizeof(int), stream);

  // degree counts
  count_k<<<cdiv(E, 256), 256, 0, stream>>>(dst_vh, cnt_h, E);
  count_k<<<cdiv(E, 256), 256, 0, stream>>>(dst_hv, cnt_v, E);

  // exclusive scans -> CSR offsets
  int nbh = cdiv(NH, 1024), nbv = cdiv(NV, 1024);
  scan_chunk_k<<<nbh, 256, 0, stream>>>(cnt_h, off_h, sums, NH);
  scan_tops_k<<<1, 64, 0, stream>>>(sums, nbh);
  scan_add_k<<<cdiv(NH, 256), 256, 0, stream>>>(off_h, sums, NH);
  scan_chunk_k<<<nbv, 256, 0, stream>>>(cnt_v, off_v, sums, NV);
  scan_tops_k<<<1, 64, 0, stream>>>(sums, nbv);
  scan_add_k<<<cdiv(NV, 256), 256, 0, stream>>>(off_v, sums, NV);

  // fill CSR (store src node ids)
  fill_k<<<cdiv(E, 256), 256, 0, stream>>>(src_vh, dst_vh, off_h, cur_h, csr_h, E);
  fill_k<<<cdiv(E, 256), 256, 0, stream>>>(src_hv, dst_hv, off_v, cur_v, csr_v, E);

  inv_k<<<cdiv(NH, 256), 256, 0, stream>>>(cnt_h, inv_h, NH);
  inv_k<<<cdiv(NV, 256), 256, 0, stream>>>(cnt_v, inv_v, NV);

  // weight transposes: WT[c] = [W_rel^T ; W_root^T]  (256 x 128)
  for (int c = 0; c < 4; ++c) {
    trans_k<<<cdiv(D * D, 256), 256, 0, stream>>>(Wc_[c][0], WT[c], D, D);
    trans_k<<<cdiv(D * D, 256), 256, 0, stream>>>(Wc_[c][1], WT[c] + D * D, D, D);
  }
  trans_k<<<cdiv(D * D, 256), 256, 0, stream>>>(W1, W1T, D, D);
  trans_k<<<cdiv(32 * D, 256), 256, 0, stream>>>(W2, W2T, 32, D);

  // ---- layer 0 (relu) ----
  agg_mean_k<<<cdiv(NH, 4), 256, 0, stream>>>(x_virus, csr_h, off_h, cnt_h, inv_h, meanb, NH);
  gemm_conv_k<<<cdiv(NH, 64), 256, 0, stream>>>(meanb, x_host, WT[0], bias_c[0], xh1, NH, 1);
  agg_mean_k<<<cdiv(NV, 4), 256, 0, stream>>>(x_host, csr_v, off_v, cnt_v, inv_v, meanb, NV);
  gemm_conv_k<<<cdiv(NV, 64), 256, 0, stream>>>(meanb, x_virus, WT[1], bias_c[1], xv1, NV, 1);

  // ---- layer 1 (no relu) ----
  agg_mean_k<<<cdiv(NH, 4), 256, 0, stream>>>(xv1, csr_h, off_h, cnt_h, inv_h, meanb, NH);
  gemm_conv_k<<<cdiv(NH, 64), 256, 0, stream>>>(meanb, xh1, WT[2], bias_c[2], xh2, NH, 0);
  agg_mean_k<<<cdiv(NV, 4), 256, 0, stream>>>(xh1, csr_v, off_v, cnt_v, inv_v, meanb, NV);
  gemm_conv_k<<<cdiv(NV, 64), 256, 0, stream>>>(meanb, xv1, WT[3], bias_c[3], xv2, NV, 0);

  // ---- decoder ----
  decoder_k<<<cdiv(L, 64), 256, 0, stream>>>(xv2, xh2, lbl_v, lbl_h, W1T, b1, W2T, b2,
                                             Wp, bp, (float*)d_out, L);
}

// Round 2
// 892.819 us; speedup vs baseline: 1.4044x; 1.4044x over previous
//
#include <hip/hip_runtime.h>

// GNN: 2-layer bipartite GraphConv + link decoder.
// Round 2: bf16 features + fp32 accumulation everywhere; MFMA GEMMs.

#define D 128

typedef float f32x4 __attribute__((ext_vector_type(4)));
typedef short s16x8 __attribute__((ext_vector_type(8)));

__device__ __forceinline__ float lo16(unsigned u) { return __uint_as_float(u << 16); }
__device__ __forceinline__ float hi16(unsigned u) { return __uint_as_float(u & 0xffff0000u); }
__device__ __forceinline__ unsigned short pkb(float f) {
  unsigned b = __float_as_uint(f);
  return (unsigned short)((b + 0x7fffu + ((b >> 16) & 1u)) >> 16);
}
__device__ __forceinline__ unsigned pk2(float a, float b) {
  return (unsigned)pkb(a) | ((unsigned)pkb(b) << 16);
}
__device__ __forceinline__ float b2f(unsigned short u) {
  return __uint_as_float(((unsigned)u) << 16);
}

// ---------------- CSR build ----------------

__global__ void count_k(const int* __restrict__ dst, int* __restrict__ cnt, int E) {
  int i = blockIdx.x * 256 + threadIdx.x;
  if (i < E) atomicAdd(&cnt[dst[i]], 1);
}

__global__ void scan_chunk_k(const int* __restrict__ in, int* __restrict__ out,
                             int* __restrict__ sums, int n) {
  __shared__ int lds[256];
  int t = threadIdx.x;
  int base = blockIdx.x * 1024 + t * 4;
  int v0 = (base + 0 < n) ? in[base + 0] : 0;
  int v1 = (base + 1 < n) ? in[base + 1] : 0;
  int v2 = (base + 2 < n) ? in[base + 2] : 0;
  int v3 = (base + 3 < n) ? in[base + 3] : 0;
  int s = v0 + v1 + v2 + v3;
  lds[t] = s;
  __syncthreads();
  for (int off = 1; off < 256; off <<= 1) {
    int x = (t >= off) ? lds[t - off] : 0;
    __syncthreads();
    lds[t] += x;
    __syncthreads();
  }
  int excl = lds[t] - s;
  if (t == 255) sums[blockIdx.x] = lds[255];
  if (base + 0 < n) out[base + 0] = excl; excl += v0;
  if (base + 1 < n) out[base + 1] = excl; excl += v1;
  if (base + 2 < n) out[base + 2] = excl; excl += v2;
  if (base + 3 < n) out[base + 3] = excl;
}

__global__ void scan_tops_k(int* __restrict__ sums, int nb) {
  if (threadIdx.x == 0 && blockIdx.x == 0) {
    int run = 0;
    for (int i = 0; i < nb; ++i) { int x = sums[i]; sums[i] = run; run += x; }
  }
}

__global__ void scan_add_k(int* __restrict__ out, const int* __restrict__ sums, int n) {
  int i = blockIdx.x * 256 + threadIdx.x;
  if (i < n) out[i] += sums[i >> 10];
}

__global__ void fill_k(const int* __restrict__ src, const int* __restrict__ dst,
                       const int* __restrict__ off, int* __restrict__ cur,
                       int* __restrict__ csr, int E) {
  int i = blockIdx.x * 256 + threadIdx.x;
  if (i < E) {
    int d = dst[i];
    int p = off[d] + atomicAdd(&cur[d], 1);
    csr[p] = src[i];
  }
}

__global__ void inv_k(const int* __restrict__ cnt, float* __restrict__ inv, int n) {
  int i = blockIdx.x * 256 + threadIdx.x;
  if (i < n) inv[i] = 1.0f / fmaxf((float)cnt[i], 1.0f);
}

// ---------------- conversions ----------------

// f32 -> bf16, 4 elems/thread
__global__ void cvt_bf16_k(const float* __restrict__ in, unsigned short* __restrict__ out, int n4) {
  int i = blockIdx.x * 256 + threadIdx.x;
  if (i < n4) {
    float4 v = ((const float4*)in)[i];
    ushort4 o;
    o.x = pkb(v.x); o.y = pkb(v.y); o.z = pkb(v.z); o.w = pkb(v.w);
    ((ushort4*)out)[i] = o;
  }
}

// Wcat[n][256] = [Wrel[n][0..127] | Wroot[n][0..127]]  (bf16)
__global__ void pack_wcat_k(const float* __restrict__ Wrel, const float* __restrict__ Wroot,
                            unsigned short* __restrict__ Wcat) {
  int idx = blockIdx.x * 256 + threadIdx.x;  // 32768
  int n = idx >> 8, k = idx & 255;
  float v = (k < 128) ? Wrel[(n << 7) + k] : Wroot[(n << 7) + k - 128];
  Wcat[idx] = pkb(v);
}

// ---------------- aggregation: one wave/dst, quarter-wave over edges ----------------

__global__ __launch_bounds__(256) void agg_mean_b(
    const unsigned short* __restrict__ xsrc, const int* __restrict__ csr,
    const int* __restrict__ off, const int* __restrict__ cnt,
    const float* __restrict__ inv, unsigned short* __restrict__ mean, int ndst) {
  int wid = blockIdx.x * 4 + (threadIdx.x >> 6);
  int lane = threadIdx.x & 63;
  if (wid >= ndst) return;
  int o = off[wid], deg = cnt[wid];
  int q = lane >> 4, sl = lane & 15;
  float acc[8] = {0.f, 0.f, 0.f, 0.f, 0.f, 0.f, 0.f, 0.f};
  for (int i = 0; i < deg; i += 4) {
    int e = i + q;
    if (e < deg) {
      int s = csr[o + e];
      uint4 v = *(const uint4*)(xsrc + (size_t)s * 128 + sl * 8);
      acc[0] += lo16(v.x); acc[1] += hi16(v.x);
      acc[2] += lo16(v.y); acc[3] += hi16(v.y);
      acc[4] += lo16(v.z); acc[5] += hi16(v.z);
      acc[6] += lo16(v.w); acc[7] += hi16(v.w);
    }
  }
#pragma unroll
  for (int j = 0; j < 8; ++j) {
    acc[j] += __shfl_xor(acc[j], 16);
    acc[j] += __shfl_xor(acc[j], 32);
  }
  if (q == 0) {
    float iv = inv[wid];
    uint4 r;
    r.x = pk2(acc[0] * iv, acc[1] * iv);
    r.y = pk2(acc[2] * iv, acc[3] * iv);
    r.z = pk2(acc[4] * iv, acc[5] * iv);
    r.w = pk2(acc[6] * iv, acc[7] * iv);
    *(uint4*)(mean + (size_t)wid * 128 + sl * 8) = r;
  }
}

// ---------------- conv GEMM (MFMA): out[n][128] = [mean|x] @ Wcat^T + b ----------------
// 128x128 tile, 4 waves (2x2), each wave 64x64 = 4x4 frags of 16x16x32.

__global__ __launch_bounds__(256) void conv_mfma_k(
    const unsigned short* __restrict__ A1, const unsigned short* __restrict__ A2,
    const unsigned short* __restrict__ Wcat, const float* __restrict__ bias,
    unsigned short* __restrict__ out, int n, int relu) {
  __shared__ uint4 Als[512];   // [128 r][4 granules of 8 bf16]
  __shared__ uint4 Bls[512];   // [128 c][4 granules]
  const int t = threadIdx.x;
  const int l = t & 63, wv = t >> 6, wr = wv >> 1, wc = wv & 1;
  const int row0 = blockIdx.x * 128;
  f32x4 acc[4][4] = {};

  for (int ch = 0; ch < 8; ++ch) {
    const unsigned short* __restrict__ Asrc = (ch < 4) ? A1 : A2;
    const int kb = (ch & 3) * 32;
    uint4 ra[2], rb[2];
#pragma unroll
    for (int i = 0; i < 2; ++i) {
      int f = t + i * 256;
      int r = f >> 2, kq = f & 3;
      int row = row0 + r; row = row < n ? row : n - 1;
      ra[i] = *(const uint4*)(Asrc + (size_t)row * 128 + kb + kq * 8);
      rb[i] = *(const uint4*)(Wcat + (size_t)r * 256 + ch * 32 + kq * 8);
    }
    __syncthreads();
#pragma unroll
    for (int i = 0; i < 2; ++i) { Als[t + i * 256] = ra[i]; Bls[t + i * 256] = rb[i]; }
    __syncthreads();
    s16x8 av[4], bv[4];
#pragma unroll
    for (int fr = 0; fr < 4; ++fr)
      av[fr] = *(const s16x8*)((const unsigned short*)Als + (wr * 64 + fr * 16 + (l & 15)) * 32 + (l >> 4) * 8);
#pragma unroll
    for (int fc = 0; fc < 4; ++fc)
      bv[fc] = *(const s16x8*)((const unsigned short*)Bls + (wc * 64 + fc * 16 + (l & 15)) * 32 + (l >> 4) * 8);
#pragma unroll
    for (int fr = 0; fr < 4; ++fr)
#pragma unroll
      for (int fc = 0; fc < 4; ++fc)
        acc[fr][fc] = __builtin_amdgcn_mfma_f32_16x16x32_bf16(av[fr], bv[fc], acc[fr][fc], 0, 0, 0);
  }

#pragma unroll
  for (int fc = 0; fc < 4; ++fc) {
    int col = wc * 64 + fc * 16 + (l & 15);
    float bb = bias[col];
#pragma unroll
    for (int fr = 0; fr < 4; ++fr) {
      int rbase = row0 + wr * 64 + fr * 16 + ((l >> 4) << 2);
#pragma unroll
      for (int reg = 0; reg < 4; ++reg) {
        int row = rbase + reg;
        if (row < n) {
          float v = acc[fr][fc][reg] + bb;
          if (relu) v = fmaxf(v, 0.f);
          out[(size_t)row * 128 + col] = pkb(v);
        }
      }
    }
  }
}

// ---------------- decoder: e = xv[lv]-xh[lh]; MFMA stage1; VALU stage2 ----------------

__global__ __launch_bounds__(256) void dec_mfma_k(
    const unsigned short* __restrict__ xv, const unsigned short* __restrict__ xh,
    const int* __restrict__ lv, const int* __restrict__ lh,
    const unsigned short* __restrict__ W1b, const float* __restrict__ b1,
    const float* __restrict__ W2, const float* __restrict__ b2,
    const float* __restrict__ Wp, const float* __restrict__ bp,
    float* __restrict__ out, int L) {
  __shared__ uint4 Els[512];
  __shared__ uint4 Bls[512];
  __shared__ unsigned short h1s[128 * 130];
  __shared__ float W2L[128 * 33];
  __shared__ int lvs[128], lhs[128];
  const int t = threadIdx.x;
  const int l = t & 63, wv = t >> 6, wr = wv >> 1, wc = wv & 1;
  const int row0 = blockIdx.x * 128;

  if (t < 128) {
    int r = row0 + t; r = r < L ? r : L - 1;
    lvs[t] = lv[r]; lhs[t] = lh[r];
  }
  for (int idx = t; idx < 4096; idx += 256) {
    int c = idx >> 7, k = idx & 127;
    W2L[k * 33 + c] = W2[idx];
  }
  f32x4 acc[4][4] = {};
  __syncthreads();

  for (int ch = 0; ch < 4; ++ch) {
    uint4 re[2], rb[2];
#pragma unroll
    for (int i = 0; i < 2; ++i) {
      int f = t + i * 256;
      int r = f >> 2, kq = f & 3;
      int iv = lvs[r], ih = lhs[r];
      uint4 a4 = *(const uint4*)(xv + (size_t)iv * 128 + ch * 32 + kq * 8);
      uint4 b4 = *(const uint4*)(xh + (size_t)ih * 128 + ch * 32 + kq * 8);
      re[i].x = pk2(lo16(a4.x) - lo16(b4.x), hi16(a4.x) - hi16(b4.x));
      re[i].y = pk2(lo16(a4.y) - lo16(b4.y), hi16(a4.y) - hi16(b4.y));
      re[i].z = pk2(lo16(a4.z) - lo16(b4.z), hi16(a4.z) - hi16(b4.z));
      re[i].w = pk2(lo16(a4.w) - lo16(b4.w), hi16(a4.w) - hi16(b4.w));
      rb[i] = *(const uint4*)(W1b + (size_t)r * 128 + ch * 32 + kq * 8);
    }
    __syncthreads();
#pragma unroll
    for (int i = 0; i < 2; ++i) { Els[t + i * 256] = re[i]; Bls[t + i * 256] = rb[i]; }
    __syncthreads();
    s16x8 av[4], bv[4];
#pragma unroll
    for (int fr = 0; fr < 4; ++fr)
      av[fr] = *(const s16x8*)((const unsigned short*)Els + (wr * 64 + fr * 16 + (l & 15)) * 32 + (l >> 4) * 8);
#pragma unroll
    for (int fc = 0; fc < 4; ++fc)
      bv[fc] = *(const s16x8*)((const unsigned short*)Bls + (wc * 64 + fc * 16 + (l & 15)) * 32 + (l >> 4) * 8);
#pragma unroll
    for (int fr = 0; fr < 4; ++fr)
#pragma unroll
      for (int fc = 0; fc < 4; ++fc)
        acc[fr][fc] = __builtin_amdgcn_mfma_f32_16x16x32_bf16(av[fr], bv[fc], acc[fr][fc], 0, 0, 0);
  }

  // h1 = relu(acc + b1) -> LDS bf16
#pragma unroll
  for (int fc = 0; fc < 4; ++fc) {
    int col = wc * 64 + fc * 16 + (l & 15);
    float bb = b1[col];
#pragma unroll
    for (int fr = 0; fr < 4; ++fr) {
      int hr = wr * 64 + fr * 16 + ((l >> 4) << 2);
#pragma unroll
      for (int reg = 0; reg < 4; ++reg) {
        float v = acc[fr][fc][reg] + bb;
        h1s[(hr + reg) * 130 + col] = pkb(fmaxf(v, 0.f));
      }
    }
  }
  __syncthreads();

  // stage2: h2 = relu(h1 @ W2^T + b2); out = h2 . Wp + bp
  const int r2 = t >> 1, c2 = (t & 1) * 16;
  float a2[16];
#pragma unroll
  for (int j = 0; j < 16; ++j) a2[j] = b2[c2 + j];
  for (int k = 0; k < 128; ++k) {
    float a = b2f(h1s[r2 * 130 + k]);
#pragma unroll
    for (int j = 0; j < 16; ++j)
      a2[j] = fmaf(a, W2L[k * 33 + c2 + j], a2[j]);
  }
  float p = 0.f;
#pragma unroll
  for (int j = 0; j < 16; ++j) p += fmaxf(a2[j], 0.f) * Wp[c2 + j];
  p += __shfl_xor(p, 1);
  int row = row0 + r2;
  if ((t & 1) == 0 && row < L) out[row] = p + bp[0];
}

// ---------------- host launcher ----------------

extern "C" void kernel_launch(void* const* d_in, const int* in_sizes, int n_in,
                              void* d_out, int out_size, void* d_ws, size_t ws_size,
                              hipStream_t stream) {
  const float* x_virus = (const float*)d_in[0];
  const float* x_host  = (const float*)d_in[1];
  const int* src_vh = (const int*)d_in[2];
  const int* dst_vh = (const int*)d_in[3];
  const int* src_hv = (const int*)d_in[4];
  const int* dst_hv = (const int*)d_in[5];
  const int* lbl_v  = (const int*)d_in[6];
  const int* lbl_h  = (const int*)d_in[7];
  const float* Wrel[4] = {(const float*)d_in[8],  (const float*)d_in[11],
                          (const float*)d_in[14], (const float*)d_in[17]};
  const float* Wroot[4] = {(const float*)d_in[10], (const float*)d_in[13],
                           (const float*)d_in[16], (const float*)d_in[19]};
  const float* bias_c[4] = {(const float*)d_in[9], (const float*)d_in[12],
                            (const float*)d_in[15], (const float*)d_in[18]};
  const float* W1 = (const float*)d_in[20];
  const float* b1 = (const float*)d_in[21];
  const float* W2 = (const float*)d_in[22];
  const float* b2 = (const float*)d_in[23];
  const float* Wp = (const float*)d_in[24];
  const float* bp = (const float*)d_in[25];

  const int NV = in_sizes[0] / D;
  const int NH = in_sizes[1] / D;
  const int E  = in_sizes[2];
  const int L  = in_sizes[6];

  // ---- workspace carve-up ----
  char* ws = (char*)d_ws;
  size_t o = 0;
  auto balloc = [&](size_t nb) { char* p = ws + o; o += (nb + 255) & ~(size_t)255; return p; };
  unsigned short* xvb   = (unsigned short*)balloc((size_t)NV * D * 2);
  unsigned short* xhb   = (unsigned short*)balloc((size_t)NH * D * 2);
  unsigned short* xv1b  = (unsigned short*)balloc((size_t)NV * D * 2);
  unsigned short* xv2b  = (unsigned short*)balloc((size_t)NV * D * 2);
  unsigned short* xh1b  = (unsigned short*)balloc((size_t)NH * D * 2);
  unsigned short* xh2b  = (unsigned short*)balloc((size_t)NH * D * 2);
  unsigned short* meanb = (unsigned short*)balloc((size_t)NV * D * 2);
  unsigned short* Wcat[4];
  for (int c = 0; c < 4; ++c) Wcat[c] = (unsigned short*)balloc(128 * 256 * 2);
  unsigned short* W1b = (unsigned short*)balloc(128 * 128 * 2);
  float* inv_h = (float*)balloc((size_t)NH * 4);
  float* inv_v = (float*)balloc((size_t)NV * 4);
  int* cnt_h = (int*)balloc((size_t)NH * 4);
  int* cur_h = (int*)balloc((size_t)NH * 4);
  int* cnt_v = (int*)balloc((size_t)NV * 4);
  int* cur_v = (int*)balloc((size_t)NV * 4);
  int* off_h = (int*)balloc((size_t)NH * 4);
  int* off_v = (int*)balloc((size_t)NV * 4);
  int* csr_h = (int*)balloc((size_t)E * 4);
  int* csr_v = (int*)balloc((size_t)E * 4);
  int* sums  = (int*)balloc(128 * 4);

  auto cdiv = [](int a, int b) { return (a + b - 1) / b; };

  // zero cnt/cur
  hipMemsetAsync(cnt_h, 0, (size_t)NH * 4, stream);
  hipMemsetAsync(cur_h, 0, (size_t)NH * 4, stream);
  hipMemsetAsync(cnt_v, 0, (size_t)NV * 4, stream);
  hipMemsetAsync(cur_v, 0, (size_t)NV * 4, stream);

  // CSR build
  count_k<<<cdiv(E, 256), 256, 0, stream>>>(dst_vh, cnt_h, E);
  count_k<<<cdiv(E, 256), 256, 0, stream>>>(dst_hv, cnt_v, E);
  int nbh = cdiv(NH, 1024), nbv = cdiv(NV, 1024);
  scan_chunk_k<<<nbh, 256, 0, stream>>>(cnt_h, off_h, sums, NH);
  scan_tops_k<<<1, 64, 0, stream>>>(sums, nbh);
  scan_add_k<<<cdiv(NH, 256), 256, 0, stream>>>(off_h, sums, NH);
  scan_chunk_k<<<nbv, 256, 0, stream>>>(cnt_v, off_v, sums, NV);
  scan_tops_k<<<1, 64, 0, stream>>>(sums, nbv);
  scan_add_k<<<cdiv(NV, 256), 256, 0, stream>>>(off_v, sums, NV);
  fill_k<<<cdiv(E, 256), 256, 0, stream>>>(src_vh, dst_vh, off_h, cur_h, csr_h, E);
  fill_k<<<cdiv(E, 256), 256, 0, stream>>>(src_hv, dst_hv, off_v, cur_v, csr_v, E);
  inv_k<<<cdiv(NH, 256), 256, 0, stream>>>(cnt_h, inv_h, NH);
  inv_k<<<cdiv(NV, 256), 256, 0, stream>>>(cnt_v, inv_v, NV);

  // conversions
  cvt_bf16_k<<<cdiv(NV * D / 4, 256), 256, 0, stream>>>(x_virus, xvb, NV * D / 4);
  cvt_bf16_k<<<cdiv(NH * D / 4, 256), 256, 0, stream>>>(x_host, xhb, NH * D / 4);
  for (int c = 0; c < 4; ++c)
    pack_wcat_k<<<128, 256, 0, stream>>>(Wrel[c], Wroot[c], Wcat[c]);
  cvt_bf16_k<<<cdiv(128 * 128 / 4, 256), 256, 0, stream>>>(W1, W1b, 128 * 128 / 4);

  // ---- layer 0 (relu) ----
  agg_mean_b<<<cdiv(NH, 4), 256, 0, stream>>>(xvb, csr_h, off_h, cnt_h, inv_h, meanb, NH);
  conv_mfma_k<<<cdiv(NH, 128), 256, 0, stream>>>(meanb, xhb, Wcat[0], bias_c[0], xh1b, NH, 1);
  agg_mean_b<<<cdiv(NV, 4), 256, 0, stream>>>(xhb, csr_v, off_v, cnt_v, inv_v, meanb, NV);
  conv_mfma_k<<<cdiv(NV, 128), 256, 0, stream>>>(meanb, xvb, Wcat[1], bias_c[1], xv1b, NV, 1);

  // ---- layer 1 (no relu) ----
  agg_mean_b<<<cdiv(NH, 4), 256, 0, stream>>>(xv1b, csr_h, off_h, cnt_h, inv_h, meanb, NH);
  conv_mfma_k<<<cdiv(NH, 128), 256, 0, stream>>>(meanb, xh1b, Wcat[2], bias_c[2], xh2b, NH, 0);
  agg_mean_b<<<cdiv(NV, 4), 256, 0, stream>>>(xh1b, csr_v, off_v, cnt_v, inv_v, meanb, NV);
  conv_mfma_k<<<cdiv(NV, 128), 256, 0, stream>>>(meanb, xv1b, Wcat[3], bias_c[3], xv2b, NV, 0);

  // ---- decoder ----
  dec_mfma_k<<<cdiv(L, 128), 256, 0, stream>>>(xv2b, xh2b, lbl_v, lbl_h, W1b, b1,
                                               W2, b2, Wp, bp, (float*)d_out, L);
}

// Round 3
// 881.133 us; speedup vs baseline: 1.4231x; 1.0133x over previous
//
#include <hip/hip_runtime.h>

// GNN: 2-layer bipartite GraphConv + link decoder.
// Round 3: phase-bucketed CSR fill (fixes partial-line scattered writes),
// 8-deep pipelined aggregation. bf16 features + fp32 accum, MFMA GEMMs.

#define D 128

typedef float f32x4 __attribute__((ext_vector_type(4)));
typedef short s16x8 __attribute__((ext_vector_type(8)));

__device__ __forceinline__ float lo16(unsigned u) { return __uint_as_float(u << 16); }
__device__ __forceinline__ float hi16(unsigned u) { return __uint_as_float(u & 0xffff0000u); }
__device__ __forceinline__ unsigned short pkb(float f) {
  unsigned b = __float_as_uint(f);
  return (unsigned short)((b + 0x7fffu + ((b >> 16) & 1u)) >> 16);
}
__device__ __forceinline__ unsigned pk2(float a, float b) {
  return (unsigned)pkb(a) | ((unsigned)pkb(b) << 16);
}
__device__ __forceinline__ float b2f(unsigned short u) {
  return __uint_as_float(((unsigned)u) << 16);
}

// ---------------- CSR build ----------------

__global__ void count_k(const int* __restrict__ dst, int* __restrict__ cnt, int E) {
  int i = blockIdx.x * 256 + threadIdx.x;
  if (i < E) atomicAdd(&cnt[dst[i]], 1);
}

__global__ void scan_chunk_k(const int* __restrict__ in, int* __restrict__ out,
                             int* __restrict__ sums, int n) {
  __shared__ int lds[256];
  int t = threadIdx.x;
  int base = blockIdx.x * 1024 + t * 4;
  int v0 = (base + 0 < n) ? in[base + 0] : 0;
  int v1 = (base + 1 < n) ? in[base + 1] : 0;
  int v2 = (base + 2 < n) ? in[base + 2] : 0;
  int v3 = (base + 3 < n) ? in[base + 3] : 0;
  int s = v0 + v1 + v2 + v3;
  lds[t] = s;
  __syncthreads();
  for (int off = 1; off < 256; off <<= 1) {
    int x = (t >= off) ? lds[t - off] : 0;
    __syncthreads();
    lds[t] += x;
    __syncthreads();
  }
  int excl = lds[t] - s;
  if (t == 255) sums[blockIdx.x] = lds[255];
  if (base + 0 < n) out[base + 0] = excl; excl += v0;
  if (base + 1 < n) out[base + 1] = excl; excl += v1;
  if (base + 2 < n) out[base + 2] = excl; excl += v2;
  if (base + 3 < n) out[base + 3] = excl;
}

__global__ void scan_tops_k(int* __restrict__ sums, int nb) {
  if (threadIdx.x == 0 && blockIdx.x == 0) {
    int run = 0;
    for (int i = 0; i < nb; ++i) { int x = sums[i]; sums[i] = run; run += x; }
  }
}

__global__ void scan_add_k(int* __restrict__ out, const int* __restrict__ sums, int n) {
  int i = blockIdx.x * 256 + threadIdx.x;
  if (i < n) out[i] += sums[i >> 10];
}

// Phase-bucketed fill: K phases over dst ranges; per phase only a small CSR
// slice is written, so L2 assembles full lines before eviction.
__global__ __launch_bounds__(256) void fill_phased_k(
    const int* __restrict__ src, const int* __restrict__ dst,
    const int* __restrict__ off, int* __restrict__ cur,
    int* __restrict__ csr, int E, int nbkt, int bsz) {
  const int stride = gridDim.x * 256;
  for (int k = 0; k < nbkt; ++k) {
    const int lo = k * bsz, hi = lo + bsz;
    for (int i = blockIdx.x * 256 + threadIdx.x; i < E; i += stride) {
      int d = dst[i];
      if (d >= lo && d < hi) {
        int p = off[d] + atomicAdd(&cur[d], 1);
        csr[p] = src[i];
      }
    }
  }
}

__global__ void inv_k(const int* __restrict__ cnt, float* __restrict__ inv, int n) {
  int i = blockIdx.x * 256 + threadIdx.x;
  if (i < n) inv[i] = 1.0f / fmaxf((float)cnt[i], 1.0f);
}

// ---------------- conversions ----------------

__global__ void cvt_bf16_k(const float* __restrict__ in, unsigned short* __restrict__ out, int n4) {
  int i = blockIdx.x * 256 + threadIdx.x;
  if (i < n4) {
    float4 v = ((const float4*)in)[i];
    ushort4 o;
    o.x = pkb(v.x); o.y = pkb(v.y); o.z = pkb(v.z); o.w = pkb(v.w);
    ((ushort4*)out)[i] = o;
  }
}

__global__ void pack_wcat_k(const float* __restrict__ Wrel, const float* __restrict__ Wroot,
                            unsigned short* __restrict__ Wcat) {
  int idx = blockIdx.x * 256 + threadIdx.x;  // 32768
  int n = idx >> 8, k = idx & 255;
  float v = (k < 128) ? Wrel[(n << 7) + k] : Wroot[(n << 7) + k - 128];
  Wcat[idx] = pkb(v);
}

// ---------------- aggregation: one wave/dst, 8 rows in flight ----------------

__global__ __launch_bounds__(256) void agg_mean_b(
    const unsigned short* __restrict__ xsrc, const int* __restrict__ csr,
    const int* __restrict__ off, const int* __restrict__ cnt,
    const float* __restrict__ inv, unsigned short* __restrict__ mean, int ndst) {
  int wid = blockIdx.x * 4 + (threadIdx.x >> 6);
  int lane = threadIdx.x & 63;
  if (wid >= ndst) return;
  int o = off[wid], deg = cnt[wid];
  int q = lane >> 4, sl = lane & 15;
  float acc[8] = {0.f, 0.f, 0.f, 0.f, 0.f, 0.f, 0.f, 0.f};
  int s0 = (q < deg) ? csr[o + q] : -1;
  int s1 = (q + 4 < deg) ? csr[o + q + 4] : -1;
  for (int i = 0; i < deg; i += 8) {
    int t0 = s0, t1 = s1;
    int e0 = i + 8 + q, e1 = i + 12 + q;
    s0 = (e0 < deg) ? csr[o + e0] : -1;
    s1 = (e1 < deg) ? csr[o + e1] : -1;
    uint4 v0, v1;
    bool b0 = (t0 >= 0), b1 = (t1 >= 0);
    if (b0) v0 = *(const uint4*)(xsrc + (size_t)t0 * 128 + sl * 8);
    if (b1) v1 = *(const uint4*)(xsrc + (size_t)t1 * 128 + sl * 8);
    if (b0) {
      acc[0] += lo16(v0.x); acc[1] += hi16(v0.x);
      acc[2] += lo16(v0.y); acc[3] += hi16(v0.y);
      acc[4] += lo16(v0.z); acc[5] += hi16(v0.z);
      acc[6] += lo16(v0.w); acc[7] += hi16(v0.w);
    }
    if (b1) {
      acc[0] += lo16(v1.x); acc[1] += hi16(v1.x);
      acc[2] += lo16(v1.y); acc[3] += hi16(v1.y);
      acc[4] += lo16(v1.z); acc[5] += hi16(v1.z);
      acc[6] += lo16(v1.w); acc[7] += hi16(v1.w);
    }
  }
#pragma unroll
  for (int j = 0; j < 8; ++j) {
    acc[j] += __shfl_xor(acc[j], 16);
    acc[j] += __shfl_xor(acc[j], 32);
  }
  if (q == 0) {
    float iv = inv[wid];
    uint4 r;
    r.x = pk2(acc[0] * iv, acc[1] * iv);
    r.y = pk2(acc[2] * iv, acc[3] * iv);
    r.z = pk2(acc[4] * iv, acc[5] * iv);
    r.w = pk2(acc[6] * iv, acc[7] * iv);
    *(uint4*)(mean + (size_t)wid * 128 + sl * 8) = r;
  }
}

// ---------------- conv GEMM (MFMA): out[n][128] = [mean|x] @ Wcat^T + b ----------------

__global__ __launch_bounds__(256) void conv_mfma_k(
    const unsigned short* __restrict__ A1, const unsigned short* __restrict__ A2,
    const unsigned short* __restrict__ Wcat, const float* __restrict__ bias,
    unsigned short* __restrict__ out, int n, int relu) {
  __shared__ uint4 Als[512];   // [128 r][4 granules of 8 bf16]
  __shared__ uint4 Bls[512];   // [128 c][4 granules]
  const int t = threadIdx.x;
  const int l = t & 63, wv = t >> 6, wr = wv >> 1, wc = wv & 1;
  const int row0 = blockIdx.x * 128;
  f32x4 acc[4][4] = {};

  for (int ch = 0; ch < 8; ++ch) {
    const unsigned short* __restrict__ Asrc = (ch < 4) ? A1 : A2;
    const int kb = (ch & 3) * 32;
    uint4 ra[2], rb[2];
#pragma unroll
    for (int i = 0; i < 2; ++i) {
      int f = t + i * 256;
      int r = f >> 2, kq = f & 3;
      int row = row0 + r; row = row < n ? row : n - 1;
      ra[i] = *(const uint4*)(Asrc + (size_t)row * 128 + kb + kq * 8);
      rb[i] = *(const uint4*)(Wcat + (size_t)r * 256 + ch * 32 + kq * 8);
    }
    __syncthreads();
#pragma unroll
    for (int i = 0; i < 2; ++i) { Als[t + i * 256] = ra[i]; Bls[t + i * 256] = rb[i]; }
    __syncthreads();
    s16x8 av[4], bv[4];
#pragma unroll
    for (int fr = 0; fr < 4; ++fr)
      av[fr] = *(const s16x8*)((const unsigned short*)Als + (wr * 64 + fr * 16 + (l & 15)) * 32 + (l >> 4) * 8);
#pragma unroll
    for (int fc = 0; fc < 4; ++fc)
      bv[fc] = *(const s16x8*)((const unsigned short*)Bls + (wc * 64 + fc * 16 + (l & 15)) * 32 + (l >> 4) * 8);
#pragma unroll
    for (int fr = 0; fr < 4; ++fr)
#pragma unroll
      for (int fc = 0; fc < 4; ++fc)
        acc[fr][fc] = __builtin_amdgcn_mfma_f32_16x16x32_bf16(av[fr], bv[fc], acc[fr][fc], 0, 0, 0);
  }

#pragma unroll
  for (int fc = 0; fc < 4; ++fc) {
    int col = wc * 64 + fc * 16 + (l & 15);
    float bb = bias[col];
#pragma unroll
    for (int fr = 0; fr < 4; ++fr) {
      int rbase = row0 + wr * 64 + fr * 16 + ((l >> 4) << 2);
#pragma unroll
      for (int reg = 0; reg < 4; ++reg) {
        int row = rbase + reg;
        if (row < n) {
          float v = acc[fr][fc][reg] + bb;
          if (relu) v = fmaxf(v, 0.f);
          out[(size_t)row * 128 + col] = pkb(v);
        }
      }
    }
  }
}

// ---------------- decoder ----------------

__global__ __launch_bounds__(256) void dec_mfma_k(
    const unsigned short* __restrict__ xv, const unsigned short* __restrict__ xh,
    const int* __restrict__ lv, const int* __restrict__ lh,
    const unsigned short* __restrict__ W1b, const float* __restrict__ b1,
    const float* __restrict__ W2, const float* __restrict__ b2,
    const float* __restrict__ Wp, const float* __restrict__ bp,
    float* __restrict__ out, int L) {
  __shared__ uint4 Els[512];
  __shared__ uint4 Bls[512];
  __shared__ unsigned short h1s[128 * 130];
  __shared__ float W2L[128 * 33];
  __shared__ int lvs[128], lhs[128];
  const int t = threadIdx.x;
  const int l = t & 63, wv = t >> 6, wr = wv >> 1, wc = wv & 1;
  const int row0 = blockIdx.x * 128;

  if (t < 128) {
    int r = row0 + t; r = r < L ? r : L - 1;
    lvs[t] = lv[r]; lhs[t] = lh[r];
  }
  for (int idx = t; idx < 4096; idx += 256) {
    int c = idx >> 7, k = idx & 127;
    W2L[k * 33 + c] = W2[idx];
  }
  f32x4 acc[4][4] = {};
  __syncthreads();

  for (int ch = 0; ch < 4; ++ch) {
    uint4 re[2], rb[2];
#pragma unroll
    for (int i = 0; i < 2; ++i) {
      int f = t + i * 256;
      int r = f >> 2, kq = f & 3;
      int iv = lvs[r], ih = lhs[r];
      uint4 a4 = *(const uint4*)(xv + (size_t)iv * 128 + ch * 32 + kq * 8);
      uint4 b4 = *(const uint4*)(xh + (size_t)ih * 128 + ch * 32 + kq * 8);
      re[i].x = pk2(lo16(a4.x) - lo16(b4.x), hi16(a4.x) - hi16(b4.x));
      re[i].y = pk2(lo16(a4.y) - lo16(b4.y), hi16(a4.y) - hi16(b4.y));
      re[i].z = pk2(lo16(a4.z) - lo16(b4.z), hi16(a4.z) - hi16(b4.z));
      re[i].w = pk2(lo16(a4.w) - lo16(b4.w), hi16(a4.w) - hi16(b4.w));
      rb[i] = *(const uint4*)(W1b + (size_t)r * 128 + ch * 32 + kq * 8);
    }
    __syncthreads();
#pragma unroll
    for (int i = 0; i < 2; ++i) { Els[t + i * 256] = re[i]; Bls[t + i * 256] = rb[i]; }
    __syncthreads();
    s16x8 av[4], bv[4];
#pragma unroll
    for (int fr = 0; fr < 4; ++fr)
      av[fr] = *(const s16x8*)((const unsigned short*)Els + (wr * 64 + fr * 16 + (l & 15)) * 32 + (l >> 4) * 8);
#pragma unroll
    for (int fc = 0; fc < 4; ++fc)
      bv[fc] = *(const s16x8*)((const unsigned short*)Bls + (wc * 64 + fc * 16 + (l & 15)) * 32 + (l >> 4) * 8);
#pragma unroll
    for (int fr = 0; fr < 4; ++fr)
#pragma unroll
      for (int fc = 0; fc < 4; ++fc)
        acc[fr][fc] = __builtin_amdgcn_mfma_f32_16x16x32_bf16(av[fr], bv[fc], acc[fr][fc], 0, 0, 0);
  }

#pragma unroll
  for (int fc = 0; fc < 4; ++fc) {
    int col = wc * 64 + fc * 16 + (l & 15);
    float bb = b1[col];
#pragma unroll
    for (int fr = 0; fr < 4; ++fr) {
      int hr = wr * 64 + fr * 16 + ((l >> 4) << 2);
#pragma unroll
      for (int reg = 0; reg < 4; ++reg) {
        float v = acc[fr][fc][reg] + bb;
        h1s[(hr + reg) * 130 + col] = pkb(fmaxf(v, 0.f));
      }
    }
  }
  __syncthreads();

  const int r2 = t >> 1, c2 = (t & 1) * 16;
  float a2[16];
#pragma unroll
  for (int j = 0; j < 16; ++j) a2[j] = b2[c2 + j];
  for (int k = 0; k < 128; ++k) {
    float a = b2f(h1s[r2 * 130 + k]);
#pragma unroll
    for (int j = 0; j < 16; ++j)
      a2[j] = fmaf(a, W2L[k * 33 + c2 + j], a2[j]);
  }
  float p = 0.f;
#pragma unroll
  for (int j = 0; j < 16; ++j) p += fmaxf(a2[j], 0.f) * Wp[c2 + j];
  p += __shfl_xor(p, 1);
  int row = row0 + r2;
  if ((t & 1) == 0 && row < L) out[row] = p + bp[0];
}

// ---------------- host launcher ----------------

extern "C" void kernel_launch(void* const* d_in, const int* in_sizes, int n_in,
                              void* d_out, int out_size, void* d_ws, size_t ws_size,
                              hipStream_t stream) {
  const float* x_virus = (const float*)d_in[0];
  const float* x_host  = (const float*)d_in[1];
  const int* src_vh = (const int*)d_in[2];
  const int* dst_vh = (const int*)d_in[3];
  const int* src_hv = (const int*)d_in[4];
  const int* dst_hv = (const int*)d_in[5];
  const int* lbl_v  = (const int*)d_in[6];
  const int* lbl_h  = (const int*)d_in[7];
  const float* Wrel[4] = {(const float*)d_in[8],  (const float*)d_in[11],
                          (const float*)d_in[14], (const float*)d_in[17]};
  const float* Wroot[4] = {(const float*)d_in[10], (const float*)d_in[13],
                           (const float*)d_in[16], (const float*)d_in[19]};
  const float* bias_c[4] = {(const float*)d_in[9], (const float*)d_in[12],
                            (const float*)d_in[15], (const float*)d_in[18]};
  const float* W1 = (const float*)d_in[20];
  const float* b1 = (const float*)d_in[21];
  const float* W2 = (const float*)d_in[22];
  const float* b2 = (const float*)d_in[23];
  const float* Wp = (const float*)d_in[24];
  const float* bp = (const float*)d_in[25];

  const int NV = in_sizes[0] / D;
  const int NH = in_sizes[1] / D;
  const int E  = in_sizes[2];
  const int L  = in_sizes[6];

  // ---- workspace carve-up ----
  char* ws = (char*)d_ws;
  size_t o = 0;
  auto balloc = [&](size_t nb) { char* p = ws + o; o += (nb + 255) & ~(size_t)255; return p; };
  unsigned short* xvb   = (unsigned short*)balloc((size_t)NV * D * 2);
  unsigned short* xhb   = (unsigned short*)balloc((size_t)NH * D * 2);
  unsigned short* xv1b  = (unsigned short*)balloc((size_t)NV * D * 2);
  unsigned short* xv2b  = (unsigned short*)balloc((size_t)NV * D * 2);
  unsigned short* xh1b  = (unsigned short*)balloc((size_t)NH * D * 2);
  unsigned short* xh2b  = (unsigned short*)balloc((size_t)NH * D * 2);
  unsigned short* meanb = (unsigned short*)balloc((size_t)NV * D * 2);
  unsigned short* Wcat[4];
  for (int c = 0; c < 4; ++c) Wcat[c] = (unsigned short*)balloc(128 * 256 * 2);
  unsigned short* W1b = (unsigned short*)balloc(128 * 128 * 2);
  float* inv_h = (float*)balloc((size_t)NH * 4);
  float* inv_v = (float*)balloc((size_t)NV * 4);
  int* cnt_h = (int*)balloc((size_t)NH * 4);
  int* cur_h = (int*)balloc((size_t)NH * 4);
  int* cnt_v = (int*)balloc((size_t)NV * 4);
  int* cur_v = (int*)balloc((size_t)NV * 4);
  int* off_h = (int*)balloc((size_t)NH * 4);
  int* off_v = (int*)balloc((size_t)NV * 4);
  int* csr_h = (int*)balloc((size_t)E * 4);
  int* csr_v = (int*)balloc((size_t)E * 4);
  int* sums  = (int*)balloc(128 * 4);

  auto cdiv = [](int a, int b) { return (a + b - 1) / b; };

  hipMemsetAsync(cnt_h, 0, (size_t)NH * 4, stream);
  hipMemsetAsync(cur_h, 0, (size_t)NH * 4, stream);
  hipMemsetAsync(cnt_v, 0, (size_t)NV * 4, stream);
  hipMemsetAsync(cur_v, 0, (size_t)NV * 4, stream);

  // CSR build
  count_k<<<cdiv(E, 256), 256, 0, stream>>>(dst_vh, cnt_h, E);
  count_k<<<cdiv(E, 256), 256, 0, stream>>>(dst_hv, cnt_v, E);
  int nbh = cdiv(NH, 1024), nbv = cdiv(NV, 1024);
  scan_chunk_k<<<nbh, 256, 0, stream>>>(cnt_h, off_h, sums, NH);
  scan_tops_k<<<1, 64, 0, stream>>>(sums, nbh);
  scan_add_k<<<cdiv(NH, 256), 256, 0, stream>>>(off_h, sums, NH);
  scan_chunk_k<<<nbv, 256, 0, stream>>>(cnt_v, off_v, sums, NV);
  scan_tops_k<<<1, 64, 0, stream>>>(sums, nbv);
  scan_add_k<<<cdiv(NV, 256), 256, 0, stream>>>(off_v, sums, NV);
  // phase-bucketed fills (8 dst-range phases, co-resident grid)
  fill_phased_k<<<1024, 256, 0, stream>>>(src_vh, dst_vh, off_h, cur_h, csr_h, E, 8, cdiv(NH, 8));
  fill_phased_k<<<1024, 256, 0, stream>>>(src_hv, dst_hv, off_v, cur_v, csr_v, E, 8, cdiv(NV, 8));
  inv_k<<<cdiv(NH, 256), 256, 0, stream>>>(cnt_h, inv_h, NH);
  inv_k<<<cdiv(NV, 256), 256, 0, stream>>>(cnt_v, inv_v, NV);

  // conversions
  cvt_bf16_k<<<cdiv(NV * D / 4, 256), 256, 0, stream>>>(x_virus, xvb, NV * D / 4);
  cvt_bf16_k<<<cdiv(NH * D / 4, 256), 256, 0, stream>>>(x_host, xhb, NH * D / 4);
  for (int c = 0; c < 4; ++c)
    pack_wcat_k<<<128, 256, 0, stream>>>(Wrel[c], Wroot[c], Wcat[c]);
  cvt_bf16_k<<<cdiv(128 * 128 / 4, 256), 256, 0, stream>>>(W1, W1b, 128 * 128 / 4);

  // ---- layer 0 (relu) ----
  agg_mean_b<<<cdiv(NH, 4), 256, 0, stream>>>(xvb, csr_h, off_h, cnt_h, inv_h, meanb, NH);
  conv_mfma_k<<<cdiv(NH, 128), 256, 0, stream>>>(meanb, xhb, Wcat[0], bias_c[0], xh1b, NH, 1);
  agg_mean_b<<<cdiv(NV, 4), 256, 0, stream>>>(xhb, csr_v, off_v, cnt_v, inv_v, meanb, NV);
  conv_mfma_k<<<cdiv(NV, 128), 256, 0, stream>>>(meanb, xvb, Wcat[1], bias_c[1], xv1b, NV, 1);

  // ---- layer 1 (no relu) ----
  agg_mean_b<<<cdiv(NH, 4), 256, 0, stream>>>(xv1b, csr_h, off_h, cnt_h, inv_h, meanb, NH);
  conv_mfma_k<<<cdiv(NH, 128), 256, 0, stream>>>(meanb, xh1b, Wcat[2], bias_c[2], xh2b, NH, 0);
  agg_mean_b<<<cdiv(NV, 4), 256, 0, stream>>>(xh1b, csr_v, off_v, cnt_v, inv_v, meanb, NV);
  conv_mfma_k<<<cdiv(NV, 128), 256, 0, stream>>>(meanb, xv1b, Wcat[3], bias_c[3], xv2b, NV, 0);

  // ---- decoder ----
  dec_mfma_k<<<cdiv(L, 128), 256, 0, stream>>>(xv2b, xh2b, lbl_v, lbl_h, W1b, b1,
                                               W2, b2, Wp, bp, (float*)d_out, L);
}

// Round 4
// 818.220 us; speedup vs baseline: 1.5325x; 1.0769x over previous
//
#include <hip/hip_runtime.h>

// GNN: 2-layer bipartite GraphConv + link decoder.
// Round 4: XCD-ownership-partitioned CSR build (blockIdx&7 sub-grids own dst
// ranges -> each CSR/cnt line dirtied by exactly one L2). bf16 + MFMA as before.

#define D 128

typedef float f32x4 __attribute__((ext_vector_type(4)));
typedef short s16x8 __attribute__((ext_vector_type(8)));

__device__ __forceinline__ float lo16(unsigned u) { return __uint_as_float(u << 16); }
__device__ __forceinline__ float hi16(unsigned u) { return __uint_as_float(u & 0xffff0000u); }
__device__ __forceinline__ unsigned short pkb(float f) {
  unsigned b = __float_as_uint(f);
  return (unsigned short)((b + 0x7fffu + ((b >> 16) & 1u)) >> 16);
}
__device__ __forceinline__ unsigned pk2(float a, float b) {
  return (unsigned)pkb(a) | ((unsigned)pkb(b) << 16);
}
__device__ __forceinline__ float b2f(unsigned short u) {
  return __uint_as_float(((unsigned)u) << 16);
}

// ---------------- CSR build (XCD-partitioned) ----------------
// Sub-grid s = blockIdx&7 scans all E edges, handles only dst in bucket s.
// With round-robin block->XCD dispatch, bucket s's cnt/cur/csr lines are
// dirtied by a single XCD's L2 -> full-line evictions, no cross-XCD sharing.

__global__ __launch_bounds__(256) void count_bkt_k(
    const int* __restrict__ dst, int* __restrict__ cnt, int E, int bsz) {
  const int sub = blockIdx.x & 7;
  const int lo = sub * bsz, hi = lo + bsz;
  const int stride = (gridDim.x >> 3) * 256;
  for (int i = (blockIdx.x >> 3) * 256 + threadIdx.x; i < E; i += stride) {
    int d = dst[i];
    if (d >= lo && d < hi) atomicAdd(&cnt[d], 1);
  }
}

__global__ void scan_chunk_k(const int* __restrict__ in, int* __restrict__ out,
                             int* __restrict__ sums, int n) {
  __shared__ int lds[256];
  int t = threadIdx.x;
  int base = blockIdx.x * 1024 + t * 4;
  int v0 = (base + 0 < n) ? in[base + 0] : 0;
  int v1 = (base + 1 < n) ? in[base + 1] : 0;
  int v2 = (base + 2 < n) ? in[base + 2] : 0;
  int v3 = (base + 3 < n) ? in[base + 3] : 0;
  int s = v0 + v1 + v2 + v3;
  lds[t] = s;
  __syncthreads();
  for (int off = 1; off < 256; off <<= 1) {
    int x = (t >= off) ? lds[t - off] : 0;
    __syncthreads();
    lds[t] += x;
    __syncthreads();
  }
  int excl = lds[t] - s;
  if (t == 255) sums[blockIdx.x] = lds[255];
  if (base + 0 < n) out[base + 0] = excl; excl += v0;
  if (base + 1 < n) out[base + 1] = excl; excl += v1;
  if (base + 2 < n) out[base + 2] = excl; excl += v2;
  if (base + 3 < n) out[base + 3] = excl;
}

__global__ void scan_tops_k(int* __restrict__ sums, int nb) {
  if (threadIdx.x == 0 && blockIdx.x == 0) {
    int run = 0;
    for (int i = 0; i < nb; ++i) { int x = sums[i]; sums[i] = run; run += x; }
  }
}

__global__ void scan_add_k(int* __restrict__ out, const int* __restrict__ sums, int n) {
  int i = blockIdx.x * 256 + threadIdx.x;
  if (i < n) out[i] += sums[i >> 10];
}

__global__ __launch_bounds__(256) void fill_bkt_k(
    const int* __restrict__ src, const int* __restrict__ dst,
    const int* __restrict__ off, int* __restrict__ cur,
    int* __restrict__ csr, int E, int bsz) {
  const int sub = blockIdx.x & 7;
  const int lo = sub * bsz, hi = lo + bsz;
  const int stride = (gridDim.x >> 3) * 256;
  for (int i = (blockIdx.x >> 3) * 256 + threadIdx.x; i < E; i += stride) {
    int d = dst[i];
    if (d >= lo && d < hi) {
      int p = off[d] + atomicAdd(&cur[d], 1);
      csr[p] = src[i];
    }
  }
}

__global__ void inv_k(const int* __restrict__ cnt, float* __restrict__ inv, int n) {
  int i = blockIdx.x * 256 + threadIdx.x;
  if (i < n) inv[i] = 1.0f / fmaxf((float)cnt[i], 1.0f);
}

// ---------------- conversions ----------------

__global__ void cvt_bf16_k(const float* __restrict__ in, unsigned short* __restrict__ out, int n4) {
  int i = blockIdx.x * 256 + threadIdx.x;
  if (i < n4) {
    float4 v = ((const float4*)in)[i];
    ushort4 o;
    o.x = pkb(v.x); o.y = pkb(v.y); o.z = pkb(v.z); o.w = pkb(v.w);
    ((ushort4*)out)[i] = o;
  }
}

__global__ void pack_wcat_k(const float* __restrict__ Wrel, const float* __restrict__ Wroot,
                            unsigned short* __restrict__ Wcat) {
  int idx = blockIdx.x * 256 + threadIdx.x;  // 32768
  int n = idx >> 8, k = idx & 255;
  float v = (k < 128) ? Wrel[(n << 7) + k] : Wroot[(n << 7) + k - 128];
  Wcat[idx] = pkb(v);
}

// ---------------- aggregation: one wave/dst, 8 rows in flight ----------------

__global__ __launch_bounds__(256) void agg_mean_b(
    const unsigned short* __restrict__ xsrc, const int* __restrict__ csr,
    const int* __restrict__ off, const int* __restrict__ cnt,
    const float* __restrict__ inv, unsigned short* __restrict__ mean, int ndst) {
  int wid = blockIdx.x * 4 + (threadIdx.x >> 6);
  int lane = threadIdx.x & 63;
  if (wid >= ndst) return;
  int o = off[wid], deg = cnt[wid];
  int q = lane >> 4, sl = lane & 15;
  float acc[8] = {0.f, 0.f, 0.f, 0.f, 0.f, 0.f, 0.f, 0.f};
  int s0 = (q < deg) ? csr[o + q] : -1;
  int s1 = (q + 4 < deg) ? csr[o + q + 4] : -1;
  for (int i = 0; i < deg; i += 8) {
    int t0 = s0, t1 = s1;
    int e0 = i + 8 + q, e1 = i + 12 + q;
    s0 = (e0 < deg) ? csr[o + e0] : -1;
    s1 = (e1 < deg) ? csr[o + e1] : -1;
    uint4 v0, v1;
    bool b0 = (t0 >= 0), b1 = (t1 >= 0);
    if (b0) v0 = *(const uint4*)(xsrc + (size_t)t0 * 128 + sl * 8);
    if (b1) v1 = *(const uint4*)(xsrc + (size_t)t1 * 128 + sl * 8);
    if (b0) {
      acc[0] += lo16(v0.x); acc[1] += hi16(v0.x);
      acc[2] += lo16(v0.y); acc[3] += hi16(v0.y);
      acc[4] += lo16(v0.z); acc[5] += hi16(v0.z);
      acc[6] += lo16(v0.w); acc[7] += hi16(v0.w);
    }
    if (b1) {
      acc[0] += lo16(v1.x); acc[1] += hi16(v1.x);
      acc[2] += lo16(v1.y); acc[3] += hi16(v1.y);
      acc[4] += lo16(v1.z); acc[5] += hi16(v1.z);
      acc[6] += lo16(v1.w); acc[7] += hi16(v1.w);
    }
  }
#pragma unroll
  for (int j = 0; j < 8; ++j) {
    acc[j] += __shfl_xor(acc[j], 16);
    acc[j] += __shfl_xor(acc[j], 32);
  }
  if (q == 0) {
    float iv = inv[wid];
    uint4 r;
    r.x = pk2(acc[0] * iv, acc[1] * iv);
    r.y = pk2(acc[2] * iv, acc[3] * iv);
    r.z = pk2(acc[4] * iv, acc[5] * iv);
    r.w = pk2(acc[6] * iv, acc[7] * iv);
    *(uint4*)(mean + (size_t)wid * 128 + sl * 8) = r;
  }
}

// ---------------- conv GEMM (MFMA): out[n][128] = [mean|x] @ Wcat^T + b ----------------

__global__ __launch_bounds__(256) void conv_mfma_k(
    const unsigned short* __restrict__ A1, const unsigned short* __restrict__ A2,
    const unsigned short* __restrict__ Wcat, const float* __restrict__ bias,
    unsigned short* __restrict__ out, int n, int relu) {
  __shared__ uint4 Als[512];   // [128 r][4 granules of 8 bf16]
  __shared__ uint4 Bls[512];   // [128 c][4 granules]
  const int t = threadIdx.x;
  const int l = t & 63, wv = t >> 6, wr = wv >> 1, wc = wv & 1;
  const int row0 = blockIdx.x * 128;
  f32x4 acc[4][4] = {};

  for (int ch = 0; ch < 8; ++ch) {
    const unsigned short* __restrict__ Asrc = (ch < 4) ? A1 : A2;
    const int kb = (ch & 3) * 32;
    uint4 ra[2], rb[2];
#pragma unroll
    for (int i = 0; i < 2; ++i) {
      int f = t + i * 256;
      int r = f >> 2, kq = f & 3;
      int row = row0 + r; row = row < n ? row : n - 1;
      ra[i] = *(const uint4*)(Asrc + (size_t)row * 128 + kb + kq * 8);
      rb[i] = *(const uint4*)(Wcat + (size_t)r * 256 + ch * 32 + kq * 8);
    }
    __syncthreads();
#pragma unroll
    for (int i = 0; i < 2; ++i) { Als[t + i * 256] = ra[i]; Bls[t + i * 256] = rb[i]; }
    __syncthreads();
    s16x8 av[4], bv[4];
#pragma unroll
    for (int fr = 0; fr < 4; ++fr)
      av[fr] = *(const s16x8*)((const unsigned short*)Als + (wr * 64 + fr * 16 + (l & 15)) * 32 + (l >> 4) * 8);
#pragma unroll
    for (int fc = 0; fc < 4; ++fc)
      bv[fc] = *(const s16x8*)((const unsigned short*)Bls + (wc * 64 + fc * 16 + (l & 15)) * 32 + (l >> 4) * 8);
#pragma unroll
    for (int fr = 0; fr < 4; ++fr)
#pragma unroll
      for (int fc = 0; fc < 4; ++fc)
        acc[fr][fc] = __builtin_amdgcn_mfma_f32_16x16x32_bf16(av[fr], bv[fc], acc[fr][fc], 0, 0, 0);
  }

#pragma unroll
  for (int fc = 0; fc < 4; ++fc) {
    int col = wc * 64 + fc * 16 + (l & 15);
    float bb = bias[col];
#pragma unroll
    for (int fr = 0; fr < 4; ++fr) {
      int rbase = row0 + wr * 64 + fr * 16 + ((l >> 4) << 2);
#pragma unroll
      for (int reg = 0; reg < 4; ++reg) {
        int row = rbase + reg;
        if (row < n) {
          float v = acc[fr][fc][reg] + bb;
          if (relu) v = fmaxf(v, 0.f);
          out[(size_t)row * 128 + col] = pkb(v);
        }
      }
    }
  }
}

// ---------------- decoder ----------------

__global__ __launch_bounds__(256) void dec_mfma_k(
    const unsigned short* __restrict__ xv, const unsigned short* __restrict__ xh,
    const int* __restrict__ lv, const int* __restrict__ lh,
    const unsigned short* __restrict__ W1b, const float* __restrict__ b1,
    const float* __restrict__ W2, const float* __restrict__ b2,
    const float* __restrict__ Wp, const float* __restrict__ bp,
    float* __restrict__ out, int L) {
  __shared__ uint4 Els[512];
  __shared__ uint4 Bls[512];
  __shared__ unsigned short h1s[128 * 130];
  __shared__ float W2L[128 * 33];
  __shared__ int lvs[128], lhs[128];
  const int t = threadIdx.x;
  const int l = t & 63, wv = t >> 6, wr = wv >> 1, wc = wv & 1;
  const int row0 = blockIdx.x * 128;

  if (t < 128) {
    int r = row0 + t; r = r < L ? r : L - 1;
    lvs[t] = lv[r]; lhs[t] = lh[r];
  }
  for (int idx = t; idx < 4096; idx += 256) {
    int c = idx >> 7, k = idx & 127;
    W2L[k * 33 + c] = W2[idx];
  }
  f32x4 acc[4][4] = {};
  __syncthreads();

  for (int ch = 0; ch < 4; ++ch) {
    uint4 re[2], rb[2];
#pragma unroll
    for (int i = 0; i < 2; ++i) {
      int f = t + i * 256;
      int r = f >> 2, kq = f & 3;
      int iv = lvs[r], ih = lhs[r];
      uint4 a4 = *(const uint4*)(xv + (size_t)iv * 128 + ch * 32 + kq * 8);
      uint4 b4 = *(const uint4*)(xh + (size_t)ih * 128 + ch * 32 + kq * 8);
      re[i].x = pk2(lo16(a4.x) - lo16(b4.x), hi16(a4.x) - hi16(b4.x));
      re[i].y = pk2(lo16(a4.y) - lo16(b4.y), hi16(a4.y) - hi16(b4.y));
      re[i].z = pk2(lo16(a4.z) - lo16(b4.z), hi16(a4.z) - hi16(b4.z));
      re[i].w = pk2(lo16(a4.w) - lo16(b4.w), hi16(a4.w) - hi16(b4.w));
      rb[i] = *(const uint4*)(W1b + (size_t)r * 128 + ch * 32 + kq * 8);
    }
    __syncthreads();
#pragma unroll
    for (int i = 0; i < 2; ++i) { Els[t + i * 256] = re[i]; Bls[t + i * 256] = rb[i]; }
    __syncthreads();
    s16x8 av[4], bv[4];
#pragma unroll
    for (int fr = 0; fr < 4; ++fr)
      av[fr] = *(const s16x8*)((const unsigned short*)Els + (wr * 64 + fr * 16 + (l & 15)) * 32 + (l >> 4) * 8);
#pragma unroll
    for (int fc = 0; fc < 4; ++fc)
      bv[fc] = *(const s16x8*)((const unsigned short*)Bls + (wc * 64 + fc * 16 + (l & 15)) * 32 + (l >> 4) * 8);
#pragma unroll
    for (int fr = 0; fr < 4; ++fr)
#pragma unroll
      for (int fc = 0; fc < 4; ++fc)
        acc[fr][fc] = __builtin_amdgcn_mfma_f32_16x16x32_bf16(av[fr], bv[fc], acc[fr][fc], 0, 0, 0);
  }

#pragma unroll
  for (int fc = 0; fc < 4; ++fc) {
    int col = wc * 64 + fc * 16 + (l & 15);
    float bb = b1[col];
#pragma unroll
    for (int fr = 0; fr < 4; ++fr) {
      int hr = wr * 64 + fr * 16 + ((l >> 4) << 2);
#pragma unroll
      for (int reg = 0; reg < 4; ++reg) {
        float v = acc[fr][fc][reg] + bb;
        h1s[(hr + reg) * 130 + col] = pkb(fmaxf(v, 0.f));
      }
    }
  }
  __syncthreads();

  const int r2 = t >> 1, c2 = (t & 1) * 16;
  float a2[16];
#pragma unroll
  for (int j = 0; j < 16; ++j) a2[j] = b2[c2 + j];
  for (int k = 0; k < 128; ++k) {
    float a = b2f(h1s[r2 * 130 + k]);
#pragma unroll
    for (int j = 0; j < 16; ++j)
      a2[j] = fmaf(a, W2L[k * 33 + c2 + j], a2[j]);
  }
  float p = 0.f;
#pragma unroll
  for (int j = 0; j < 16; ++j) p += fmaxf(a2[j], 0.f) * Wp[c2 + j];
  p += __shfl_xor(p, 1);
  int row = row0 + r2;
  if ((t & 1) == 0 && row < L) out[row] = p + bp[0];
}

// ---------------- host launcher ----------------

extern "C" void kernel_launch(void* const* d_in, const int* in_sizes, int n_in,
                              void* d_out, int out_size, void* d_ws, size_t ws_size,
                              hipStream_t stream) {
  const float* x_virus = (const float*)d_in[0];
  const float* x_host  = (const float*)d_in[1];
  const int* src_vh = (const int*)d_in[2];
  const int* dst_vh = (const int*)d_in[3];
  const int* src_hv = (const int*)d_in[4];
  const int* dst_hv = (const int*)d_in[5];
  const int* lbl_v  = (const int*)d_in[6];
  const int* lbl_h  = (const int*)d_in[7];
  const float* Wrel[4] = {(const float*)d_in[8],  (const float*)d_in[11],
                          (const float*)d_in[14], (const float*)d_in[17]};
  const float* Wroot[4] = {(const float*)d_in[10], (const float*)d_in[13],
                           (const float*)d_in[16], (const float*)d_in[19]};
  const float* bias_c[4] = {(const float*)d_in[9], (const float*)d_in[12],
                            (const float*)d_in[15], (const float*)d_in[18]};
  const float* W1 = (const float*)d_in[20];
  const float* b1 = (const float*)d_in[21];
  const float* W2 = (const float*)d_in[22];
  const float* b2 = (const float*)d_in[23];
  const float* Wp = (const float*)d_in[24];
  const float* bp = (const float*)d_in[25];

  const int NV = in_sizes[0] / D;
  const int NH = in_sizes[1] / D;
  const int E  = in_sizes[2];
  const int L  = in_sizes[6];

  // ---- workspace carve-up ----
  char* ws = (char*)d_ws;
  size_t o = 0;
  auto balloc = [&](size_t nb) { char* p = ws + o; o += (nb + 255) & ~(size_t)255; return p; };
  unsigned short* xvb   = (unsigned short*)balloc((size_t)NV * D * 2);
  unsigned short* xhb   = (unsigned short*)balloc((size_t)NH * D * 2);
  unsigned short* xv1b  = (unsigned short*)balloc((size_t)NV * D * 2);
  unsigned short* xv2b  = (unsigned short*)balloc((size_t)NV * D * 2);
  unsigned short* xh1b  = (unsigned short*)balloc((size_t)NH * D * 2);
  unsigned short* xh2b  = (unsigned short*)balloc((size_t)NH * D * 2);
  unsigned short* meanb = (unsigned short*)balloc((size_t)NV * D * 2);
  unsigned short* Wcat[4];
  for (int c = 0; c < 4; ++c) Wcat[c] = (unsigned short*)balloc(128 * 256 * 2);
  unsigned short* W1b = (unsigned short*)balloc(128 * 128 * 2);
  float* inv_h = (float*)balloc((size_t)NH * 4);
  float* inv_v = (float*)balloc((size_t)NV * 4);
  int* cnt_h = (int*)balloc((size_t)NH * 4);
  int* cur_h = (int*)balloc((size_t)NH * 4);
  int* cnt_v = (int*)balloc((size_t)NV * 4);
  int* cur_v = (int*)balloc((size_t)NV * 4);
  int* off_h = (int*)balloc((size_t)NH * 4);
  int* off_v = (int*)balloc((size_t)NV * 4);
  int* csr_h = (int*)balloc((size_t)E * 4);
  int* csr_v = (int*)balloc((size_t)E * 4);
  int* sums  = (int*)balloc(128 * 4);

  auto cdiv = [](int a, int b) { return (a + b - 1) / b; };
  const int bszh = cdiv(NH, 8), bszv = cdiv(NV, 8);

  hipMemsetAsync(cnt_h, 0, (size_t)NH * 4, stream);
  hipMemsetAsync(cur_h, 0, (size_t)NH * 4, stream);
  hipMemsetAsync(cnt_v, 0, (size_t)NV * 4, stream);
  hipMemsetAsync(cur_v, 0, (size_t)NV * 4, stream);

  // CSR build (XCD-partitioned counts and fills)
  count_bkt_k<<<1024, 256, 0, stream>>>(dst_vh, cnt_h, E, bszh);
  count_bkt_k<<<1024, 256, 0, stream>>>(dst_hv, cnt_v, E, bszv);
  int nbh = cdiv(NH, 1024), nbv = cdiv(NV, 1024);
  scan_chunk_k<<<nbh, 256, 0, stream>>>(cnt_h, off_h, sums, NH);
  scan_tops_k<<<1, 64, 0, stream>>>(sums, nbh);
  scan_add_k<<<cdiv(NH, 256), 256, 0, stream>>>(off_h, sums, NH);
  scan_chunk_k<<<nbv, 256, 0, stream>>>(cnt_v, off_v, sums, NV);
  scan_tops_k<<<1, 64, 0, stream>>>(sums, nbv);
  scan_add_k<<<cdiv(NV, 256), 256, 0, stream>>>(off_v, sums, NV);
  fill_bkt_k<<<1024, 256, 0, stream>>>(src_vh, dst_vh, off_h, cur_h, csr_h, E, bszh);
  fill_bkt_k<<<1024, 256, 0, stream>>>(src_hv, dst_hv, off_v, cur_v, csr_v, E, bszv);
  inv_k<<<cdiv(NH, 256), 256, 0, stream>>>(cnt_h, inv_h, NH);
  inv_k<<<cdiv(NV, 256), 256, 0, stream>>>(cnt_v, inv_v, NV);

  // conversions
  cvt_bf16_k<<<cdiv(NV * D / 4, 256), 256, 0, stream>>>(x_virus, xvb, NV * D / 4);
  cvt_bf16_k<<<cdiv(NH * D / 4, 256), 256, 0, stream>>>(x_host, xhb, NH * D / 4);
  for (int c = 0; c < 4; ++c)
    pack_wcat_k<<<128, 256, 0, stream>>>(Wrel[c], Wroot[c], Wcat[c]);
  cvt_bf16_k<<<cdiv(128 * 128 / 4, 256), 256, 0, stream>>>(W1, W1b, 128 * 128 / 4);

  // ---- layer 0 (relu) ----
  agg_mean_b<<<cdiv(NH, 4), 256, 0, stream>>>(xvb, csr_h, off_h, cnt_h, inv_h, meanb, NH);
  conv_mfma_k<<<cdiv(NH, 128), 256, 0, stream>>>(meanb, xhb, Wcat[0], bias_c[0], xh1b, NH, 1);
  agg_mean_b<<<cdiv(NV, 4), 256, 0, stream>>>(xhb, csr_v, off_v, cnt_v, inv_v, meanb, NV);
  conv_mfma_k<<<cdiv(NV, 128), 256, 0, stream>>>(meanb, xvb, Wcat[1], bias_c[1], xv1b, NV, 1);

  // ---- layer 1 (no relu) ----
  agg_mean_b<<<cdiv(NH, 4), 256, 0, stream>>>(xv1b, csr_h, off_h, cnt_h, inv_h, meanb, NH);
  conv_mfma_k<<<cdiv(NH, 128), 256, 0, stream>>>(meanb, xh1b, Wcat[2], bias_c[2], xh2b, NH, 0);
  agg_mean_b<<<cdiv(NV, 4), 256, 0, stream>>>(xh1b, csr_v, off_v, cnt_v, inv_v, meanb, NV);
  conv_mfma_k<<<cdiv(NV, 128), 256, 0, stream>>>(meanb, xv1b, Wcat[3], bias_c[3], xv2b, NV, 0);

  // ---- decoder ----
  dec_mfma_k<<<cdiv(L, 128), 256, 0, stream>>>(xv2b, xh2b, lbl_v, lbl_h, W1b, b1,
                                               W2, b2, Wp, bp, (float*)d_out, L);
}

// Round 5
// 799.744 us; speedup vs baseline: 1.5679x; 1.0231x over previous
//
#include <hip/hip_runtime.h>

// GNN: 2-layer bipartite GraphConv + link decoder.
// Round 5: barrier-free conv/decoder MFMA (B operands direct from L2-resident
// global, A fragments direct-gathered, per-wave-private h1 LDS slice,
// stage-2 decoder via MFMA). Agg: 16 rows in flight. CSR build as R4.

#define D 128

typedef float f32x4 __attribute__((ext_vector_type(4)));
typedef short s16x8 __attribute__((ext_vector_type(8)));

__device__ __forceinline__ float lo16(unsigned u) { return __uint_as_float(u << 16); }
__device__ __forceinline__ float hi16(unsigned u) { return __uint_as_float(u & 0xffff0000u); }
__device__ __forceinline__ unsigned short pkb(float f) {
  unsigned b = __float_as_uint(f);
  return (unsigned short)((b + 0x7fffu + ((b >> 16) & 1u)) >> 16);
}
__device__ __forceinline__ unsigned pk2(float a, float b) {
  return (unsigned)pkb(a) | ((unsigned)pkb(b) << 16);
}
__device__ __forceinline__ float b2f(unsigned short u) {
  return __uint_as_float(((unsigned)u) << 16);
}

union U4S8 { uint4 u; s16x8 s; };

// ---------------- CSR build (XCD-partitioned, from R4) ----------------

__global__ __launch_bounds__(256) void count_bkt_k(
    const int* __restrict__ dst, int* __restrict__ cnt, int E, int bsz) {
  const int sub = blockIdx.x & 7;
  const int lo = sub * bsz, hi = lo + bsz;
  const int stride = (gridDim.x >> 3) * 256;
  for (int i = (blockIdx.x >> 3) * 256 + threadIdx.x; i < E; i += stride) {
    int d = dst[i];
    if (d >= lo && d < hi) atomicAdd(&cnt[d], 1);
  }
}

__global__ void scan_chunk_k(const int* __restrict__ in, int* __restrict__ out,
                             int* __restrict__ sums, int n) {
  __shared__ int lds[256];
  int t = threadIdx.x;
  int base = blockIdx.x * 1024 + t * 4;
  int v0 = (base + 0 < n) ? in[base + 0] : 0;
  int v1 = (base + 1 < n) ? in[base + 1] : 0;
  int v2 = (base + 2 < n) ? in[base + 2] : 0;
  int v3 = (base + 3 < n) ? in[base + 3] : 0;
  int s = v0 + v1 + v2 + v3;
  lds[t] = s;
  __syncthreads();
  for (int off = 1; off < 256; off <<= 1) {
    int x = (t >= off) ? lds[t - off] : 0;
    __syncthreads();
    lds[t] += x;
    __syncthreads();
  }
  int excl = lds[t] - s;
  if (t == 255) sums[blockIdx.x] = lds[255];
  if (base + 0 < n) out[base + 0] = excl; excl += v0;
  if (base + 1 < n) out[base + 1] = excl; excl += v1;
  if (base + 2 < n) out[base + 2] = excl; excl += v2;
  if (base + 3 < n) out[base + 3] = excl;
}

__global__ void scan_tops_k(int* __restrict__ sums, int nb) {
  if (threadIdx.x == 0 && blockIdx.x == 0) {
    int run = 0;
    for (int i = 0; i < nb; ++i) { int x = sums[i]; sums[i] = run; run += x; }
  }
}

__global__ void scan_add_k(int* __restrict__ out, const int* __restrict__ sums, int n) {
  int i = blockIdx.x * 256 + threadIdx.x;
  if (i < n) out[i] += sums[i >> 10];
}

__global__ __launch_bounds__(256) void fill_bkt_k(
    const int* __restrict__ src, const int* __restrict__ dst,
    const int* __restrict__ off, int* __restrict__ cur,
    int* __restrict__ csr, int E, int bsz) {
  const int sub = blockIdx.x & 7;
  const int lo = sub * bsz, hi = lo + bsz;
  const int stride = (gridDim.x >> 3) * 256;
  for (int i = (blockIdx.x >> 3) * 256 + threadIdx.x; i < E; i += stride) {
    int d = dst[i];
    if (d >= lo && d < hi) {
      int p = off[d] + atomicAdd(&cur[d], 1);
      csr[p] = src[i];
    }
  }
}

__global__ void inv_k(const int* __restrict__ cnt, float* __restrict__ inv, int n) {
  int i = blockIdx.x * 256 + threadIdx.x;
  if (i < n) inv[i] = 1.0f / fmaxf((float)cnt[i], 1.0f);
}

// ---------------- conversions ----------------

__global__ void cvt_bf16_k(const float* __restrict__ in, unsigned short* __restrict__ out, int n4) {
  int i = blockIdx.x * 256 + threadIdx.x;
  if (i < n4) {
    float4 v = ((const float4*)in)[i];
    ushort4 o;
    o.x = pkb(v.x); o.y = pkb(v.y); o.z = pkb(v.z); o.w = pkb(v.w);
    ((ushort4*)out)[i] = o;
  }
}

__global__ void pack_wcat_k(const float* __restrict__ Wrel, const float* __restrict__ Wroot,
                            unsigned short* __restrict__ Wcat) {
  int idx = blockIdx.x * 256 + threadIdx.x;  // 32768
  int n = idx >> 8, k = idx & 255;
  float v = (k < 128) ? Wrel[(n << 7) + k] : Wroot[(n << 7) + k - 128];
  Wcat[idx] = pkb(v);
}

// ---------------- aggregation: one wave/dst, 16 rows in flight ----------------

__global__ __launch_bounds__(256) void agg_mean_b(
    const unsigned short* __restrict__ xsrc, const int* __restrict__ csr,
    const int* __restrict__ off, const int* __restrict__ cnt,
    const float* __restrict__ inv, unsigned short* __restrict__ mean, int ndst) {
  int wid = blockIdx.x * 4 + (threadIdx.x >> 6);
  int lane = threadIdx.x & 63;
  if (wid >= ndst) return;
  int o = off[wid], deg = cnt[wid];
  int q = lane >> 4, sl = lane & 15;
  float acc[8] = {0.f, 0.f, 0.f, 0.f, 0.f, 0.f, 0.f, 0.f};
  int sN[4];
#pragma unroll
  for (int j = 0; j < 4; ++j) {
    int e = j * 4 + q;
    sN[j] = (e < deg) ? csr[o + e] : -1;
  }
  for (int i = 0; i < deg; i += 16) {
    int cu[4];
#pragma unroll
    for (int j = 0; j < 4; ++j) {
      cu[j] = sN[j];
      int e = i + 16 + j * 4 + q;
      sN[j] = (e < deg) ? csr[o + e] : -1;
    }
    uint4 v[4];
#pragma unroll
    for (int j = 0; j < 4; ++j)
      if (cu[j] >= 0) v[j] = *(const uint4*)(xsrc + (size_t)cu[j] * 128 + sl * 8);
#pragma unroll
    for (int j = 0; j < 4; ++j) {
      if (cu[j] >= 0) {
        acc[0] += lo16(v[j].x); acc[1] += hi16(v[j].x);
        acc[2] += lo16(v[j].y); acc[3] += hi16(v[j].y);
        acc[4] += lo16(v[j].z); acc[5] += hi16(v[j].z);
        acc[6] += lo16(v[j].w); acc[7] += hi16(v[j].w);
      }
    }
  }
#pragma unroll
  for (int j = 0; j < 8; ++j) {
    acc[j] += __shfl_xor(acc[j], 16);
    acc[j] += __shfl_xor(acc[j], 32);
  }
  if (q == 0) {
    float iv = inv[wid];
    uint4 r;
    r.x = pk2(acc[0] * iv, acc[1] * iv);
    r.y = pk2(acc[2] * iv, acc[3] * iv);
    r.z = pk2(acc[4] * iv, acc[5] * iv);
    r.w = pk2(acc[6] * iv, acc[7] * iv);
    *(uint4*)(mean + (size_t)wid * 128 + sl * 8) = r;
  }
}

// ---------------- conv GEMM (MFMA, no LDS/barriers) ----------------
// out[n][128] = [mean|x] @ Wcat^T + b. 128 rows/block, 4 waves: wave w owns
// rows w*32..w*32+31 (2 row-frags) x 128 cols (8 col-frags). B from L2.

__global__ __launch_bounds__(256) void conv_mfma_k(
    const unsigned short* __restrict__ A1, const unsigned short* __restrict__ A2,
    const unsigned short* __restrict__ Wcat, const float* __restrict__ bias,
    unsigned short* __restrict__ out, int n, int relu) {
  const int t = threadIdx.x;
  const int l = t & 63, wv = t >> 6;
  const int row0 = blockIdx.x * 128 + wv * 32;
  const int g = l >> 4;           // k-granule 0..3
  f32x4 acc[2][8] = {};

  int rowa[2];
#pragma unroll
  for (int fr = 0; fr < 2; ++fr) {
    int r = row0 + fr * 16 + (l & 15);
    rowa[fr] = r < n ? r : n - 1;
  }

  for (int ch = 0; ch < 8; ++ch) {
    const unsigned short* __restrict__ Asrc = (ch < 4) ? A1 : A2;
    const int kb = (ch & 3) * 32;
    s16x8 av[2];
#pragma unroll
    for (int fr = 0; fr < 2; ++fr)
      av[fr] = *(const s16x8*)(Asrc + (size_t)rowa[fr] * 128 + kb + g * 8);
#pragma unroll
    for (int fc = 0; fc < 8; ++fc) {
      int col = fc * 16 + (l & 15);
      s16x8 bv = *(const s16x8*)(Wcat + (size_t)col * 256 + ch * 32 + g * 8);
#pragma unroll
      for (int fr = 0; fr < 2; ++fr)
        acc[fr][fc] = __builtin_amdgcn_mfma_f32_16x16x32_bf16(av[fr], bv, acc[fr][fc], 0, 0, 0);
    }
  }

#pragma unroll
  for (int fc = 0; fc < 8; ++fc) {
    int col = fc * 16 + (l & 15);
    float bb = bias[col];
#pragma unroll
    for (int fr = 0; fr < 2; ++fr) {
      int rbase = row0 + fr * 16 + g * 4;
#pragma unroll
      for (int reg = 0; reg < 4; ++reg) {
        int row = rbase + reg;
        if (row < n) {
          float v = acc[fr][fc][reg] + bb;
          if (relu) v = fmaxf(v, 0.f);
          out[(size_t)row * 128 + col] = pkb(v);
        }
      }
    }
  }
}

// ---------------- decoder (barrier-free) ----------------
// 64 rows/block, 4 waves; wave w owns rows w*16..w*16+15.
// stage1: e = xv[lv]-xh[lh] (direct gather into A-frags), h1 = relu(e@W1^T+b1)
// -> per-wave LDS slice. stage2: h2 = relu(h1@W2^T+b2) via MFMA, out = h2.Wp+bp.

__global__ __launch_bounds__(256) void dec_mfma_k(
    const unsigned short* __restrict__ xv, const unsigned short* __restrict__ xh,
    const int* __restrict__ lv, const int* __restrict__ lh,
    const unsigned short* __restrict__ W1b, const float* __restrict__ b1,
    const unsigned short* __restrict__ W2b, const float* __restrict__ b2,
    const float* __restrict__ Wp, const float* __restrict__ bp,
    float* __restrict__ out, int L) {
  __shared__ unsigned short h1s[64 * 132];
  const int t = threadIdx.x;
  const int l = t & 63, wv = t >> 6;
  const int g = l >> 4;
  const int row0 = blockIdx.x * 64 + wv * 16;

  int rowc = row0 + (l & 15);
  rowc = rowc < L ? rowc : L - 1;
  const int iv = lv[rowc], ih = lh[rowc];

  f32x4 acc[8] = {};
  for (int ch = 0; ch < 4; ++ch) {
    uint4 a4 = *(const uint4*)(xv + (size_t)iv * 128 + ch * 32 + g * 8);
    uint4 b4 = *(const uint4*)(xh + (size_t)ih * 128 + ch * 32 + g * 8);
    U4S8 e;
    e.u.x = pk2(lo16(a4.x) - lo16(b4.x), hi16(a4.x) - hi16(b4.x));
    e.u.y = pk2(lo16(a4.y) - lo16(b4.y), hi16(a4.y) - hi16(b4.y));
    e.u.z = pk2(lo16(a4.z) - lo16(b4.z), hi16(a4.z) - hi16(b4.z));
    e.u.w = pk2(lo16(a4.w) - lo16(b4.w), hi16(a4.w) - hi16(b4.w));
#pragma unroll
    for (int fc = 0; fc < 8; ++fc) {
      int col = fc * 16 + (l & 15);
      s16x8 bv = *(const s16x8*)(W1b + (size_t)col * 128 + ch * 32 + g * 8);
      acc[fc] = __builtin_amdgcn_mfma_f32_16x16x32_bf16(e.s, bv, acc[fc], 0, 0, 0);
    }
  }

  // h1 -> per-wave LDS slice (rows wv*16.. exclusively ours; no barrier)
#pragma unroll
  for (int fc = 0; fc < 8; ++fc) {
    int col = fc * 16 + (l & 15);
    float bb = b1[col];
#pragma unroll
    for (int reg = 0; reg < 4; ++reg) {
      int hr = wv * 16 + g * 4 + reg;
      h1s[hr * 132 + col] = pkb(fmaxf(acc[fc][reg] + bb, 0.f));
    }
  }

  // stage2 MFMA: A = h1 (own rows), B = W2b [32][128]
  f32x4 acc2[2] = {};
  for (int kc = 0; kc < 4; ++kc) {
    s16x8 av2 = *(const s16x8*)(h1s + (wv * 16 + (l & 15)) * 132 + kc * 32 + g * 8);
#pragma unroll
    for (int fc = 0; fc < 2; ++fc) {
      s16x8 bv2 = *(const s16x8*)(W2b + (size_t)(fc * 16 + (l & 15)) * 128 + kc * 32 + g * 8);
      acc2[fc] = __builtin_amdgcn_mfma_f32_16x16x32_bf16(av2, bv2, acc2[fc], 0, 0, 0);
    }
  }

  float p[4] = {0.f, 0.f, 0.f, 0.f};
#pragma unroll
  for (int fc = 0; fc < 2; ++fc) {
    int col = fc * 16 + (l & 15);
    float wp = Wp[col], bb = b2[col];
#pragma unroll
    for (int reg = 0; reg < 4; ++reg)
      p[reg] += fmaxf(acc2[fc][reg] + bb, 0.f) * wp;
  }
#pragma unroll
  for (int reg = 0; reg < 4; ++reg) {
    p[reg] += __shfl_xor(p[reg], 1);
    p[reg] += __shfl_xor(p[reg], 2);
    p[reg] += __shfl_xor(p[reg], 4);
    p[reg] += __shfl_xor(p[reg], 8);
  }
  if ((l & 15) == 0) {
    float bb = bp[0];
#pragma unroll
    for (int reg = 0; reg < 4; ++reg) {
      int row = row0 + g * 4 + reg;
      if (row < L) out[row] = p[reg] + bb;
    }
  }
}

// ---------------- host launcher ----------------

extern "C" void kernel_launch(void* const* d_in, const int* in_sizes, int n_in,
                              void* d_out, int out_size, void* d_ws, size_t ws_size,
                              hipStream_t stream) {
  const float* x_virus = (const float*)d_in[0];
  const float* x_host  = (const float*)d_in[1];
  const int* src_vh = (const int*)d_in[2];
  const int* dst_vh = (const int*)d_in[3];
  const int* src_hv = (const int*)d_in[4];
  const int* dst_hv = (const int*)d_in[5];
  const int* lbl_v  = (const int*)d_in[6];
  const int* lbl_h  = (const int*)d_in[7];
  const float* Wrel[4] = {(const float*)d_in[8],  (const float*)d_in[11],
                          (const float*)d_in[14], (const float*)d_in[17]};
  const float* Wroot[4] = {(const float*)d_in[10], (const float*)d_in[13],
                           (const float*)d_in[16], (const float*)d_in[19]};
  const float* bias_c[4] = {(const float*)d_in[9], (const float*)d_in[12],
                            (const float*)d_in[15], (const float*)d_in[18]};
  const float* W1 = (const float*)d_in[20];
  const float* b1 = (const float*)d_in[21];
  const float* W2 = (const float*)d_in[22];
  const float* b2 = (const float*)d_in[23];
  const float* Wp = (const float*)d_in[24];
  const float* bp = (const float*)d_in[25];

  const int NV = in_sizes[0] / D;
  const int NH = in_sizes[1] / D;
  const int E  = in_sizes[2];
  const int L  = in_sizes[6];

  // ---- workspace carve-up ----
  char* ws = (char*)d_ws;
  size_t o = 0;
  auto balloc = [&](size_t nb) { char* p = ws + o; o += (nb + 255) & ~(size_t)255; return p; };
  unsigned short* xvb   = (unsigned short*)balloc((size_t)NV * D * 2);
  unsigned short* xhb   = (unsigned short*)balloc((size_t)NH * D * 2);
  unsigned short* xv1b  = (unsigned short*)balloc((size_t)NV * D * 2);
  unsigned short* xv2b  = (unsigned short*)balloc((size_t)NV * D * 2);
  unsigned short* xh1b  = (unsigned short*)balloc((size_t)NH * D * 2);
  unsigned short* xh2b  = (unsigned short*)balloc((size_t)NH * D * 2);
  unsigned short* meanb = (unsigned short*)balloc((size_t)NV * D * 2);
  unsigned short* Wcat[4];
  for (int c = 0; c < 4; ++c) Wcat[c] = (unsigned short*)balloc(128 * 256 * 2);
  unsigned short* W1b = (unsigned short*)balloc(128 * 128 * 2);
  unsigned short* W2b = (unsigned short*)balloc(32 * 128 * 2);
  float* inv_h = (float*)balloc((size_t)NH * 4);
  float* inv_v = (float*)balloc((size_t)NV * 4);
  int* cnt_h = (int*)balloc((size_t)NH * 4);
  int* cur_h = (int*)balloc((size_t)NH * 4);
  int* cnt_v = (int*)balloc((size_t)NV * 4);
  int* cur_v = (int*)balloc((size_t)NV * 4);
  int* off_h = (int*)balloc((size_t)NH * 4);
  int* off_v = (int*)balloc((size_t)NV * 4);
  int* csr_h = (int*)balloc((size_t)E * 4);
  int* csr_v = (int*)balloc((size_t)E * 4);
  int* sums  = (int*)balloc(128 * 4);

  auto cdiv = [](int a, int b) { return (a + b - 1) / b; };
  const int bszh = cdiv(NH, 8), bszv = cdiv(NV, 8);

  hipMemsetAsync(cnt_h, 0, (size_t)NH * 4, stream);
  hipMemsetAsync(cur_h, 0, (size_t)NH * 4, stream);
  hipMemsetAsync(cnt_v, 0, (size_t)NV * 4, stream);
  hipMemsetAsync(cur_v, 0, (size_t)NV * 4, stream);

  // CSR build (XCD-partitioned counts and fills)
  count_bkt_k<<<1024, 256, 0, stream>>>(dst_vh, cnt_h, E, bszh);
  count_bkt_k<<<1024, 256, 0, stream>>>(dst_hv, cnt_v, E, bszv);
  int nbh = cdiv(NH, 1024), nbv = cdiv(NV, 1024);
  scan_chunk_k<<<nbh, 256, 0, stream>>>(cnt_h, off_h, sums, NH);
  scan_tops_k<<<1, 64, 0, stream>>>(sums, nbh);
  scan_add_k<<<cdiv(NH, 256), 256, 0, stream>>>(off_h, sums, NH);
  scan_chunk_k<<<nbv, 256, 0, stream>>>(cnt_v, off_v, sums, NV);
  scan_tops_k<<<1, 64, 0, stream>>>(sums, nbv);
  scan_add_k<<<cdiv(NV, 256), 256, 0, stream>>>(off_v, sums, NV);
  fill_bkt_k<<<1024, 256, 0, stream>>>(src_vh, dst_vh, off_h, cur_h, csr_h, E, bszh);
  fill_bkt_k<<<1024, 256, 0, stream>>>(src_hv, dst_hv, off_v, cur_v, csr_v, E, bszv);
  inv_k<<<cdiv(NH, 256), 256, 0, stream>>>(cnt_h, inv_h, NH);
  inv_k<<<cdiv(NV, 256), 256, 0, stream>>>(cnt_v, inv_v, NV);

  // conversions
  cvt_bf16_k<<<cdiv(NV * D / 4, 256), 256, 0, stream>>>(x_virus, xvb, NV * D / 4);
  cvt_bf16_k<<<cdiv(NH * D / 4, 256), 256, 0, stream>>>(x_host, xhb, NH * D / 4);
  for (int c = 0; c < 4; ++c)
    pack_wcat_k<<<128, 256, 0, stream>>>(Wrel[c], Wroot[c], Wcat[c]);
  cvt_bf16_k<<<cdiv(128 * 128 / 4, 256), 256, 0, stream>>>(W1, W1b, 128 * 128 / 4);
  cvt_bf16_k<<<cdiv(32 * 128 / 4, 256), 256, 0, stream>>>(W2, W2b, 32 * 128 / 4);

  // ---- layer 0 (relu) ----
  agg_mean_b<<<cdiv(NH, 4), 256, 0, stream>>>(xvb, csr_h, off_h, cnt_h, inv_h, meanb, NH);
  conv_mfma_k<<<cdiv(NH, 128), 256, 0, stream>>>(meanb, xhb, Wcat[0], bias_c[0], xh1b, NH, 1);
  agg_mean_b<<<cdiv(NV, 4), 256, 0, stream>>>(xhb, csr_v, off_v, cnt_v, inv_v, meanb, NV);
  conv_mfma_k<<<cdiv(NV, 128), 256, 0, stream>>>(meanb, xvb, Wcat[1], bias_c[1], xv1b, NV, 1);

  // ---- layer 1 (no relu) ----
  agg_mean_b<<<cdiv(NH, 4), 256, 0, stream>>>(xv1b, csr_h, off_h, cnt_h, inv_h, meanb, NH);
  conv_mfma_k<<<cdiv(NH, 128), 256, 0, stream>>>(meanb, xh1b, Wcat[2], bias_c[2], xh2b, NH, 0);
  agg_mean_b<<<cdiv(NV, 4), 256, 0, stream>>>(xh1b, csr_v, off_v, cnt_v, inv_v, meanb, NV);
  conv_mfma_k<<<cdiv(NV, 128), 256, 0, stream>>>(meanb, xv1b, Wcat[3], bias_c[3], xv2b, NV, 0);

  // ---- decoder ----
  dec_mfma_k<<<cdiv(L, 64), 256, 0, stream>>>(xv2b, xh2b, lbl_v, lbl_h, W1b, b1,
                                              W2b, b2, Wp, bp, (float*)d_out, L);
}

// Round 6
// 573.504 us; speedup vs baseline: 2.1864x; 1.3945x over previous
//
#include <hip/hip_runtime.h>

// GNN: 2-layer bipartite GraphConv + link decoder.
// Round 6: atomic-free CSR build via counting-sort partition
// (LDS histograms + matrix scan + binned scatter + per-bin finalize).
// bf16 features + fp32 accum, barrier-free MFMA conv/decoder (R5).

#define D 128
#define PGB 256   // partition grid blocks

typedef float f32x4 __attribute__((ext_vector_type(4)));
typedef short s16x8 __attribute__((ext_vector_type(8)));

__device__ __forceinline__ float lo16(unsigned u) { return __uint_as_float(u << 16); }
__device__ __forceinline__ float hi16(unsigned u) { return __uint_as_float(u & 0xffff0000u); }
__device__ __forceinline__ unsigned short pkb(float f) {
  unsigned b = __float_as_uint(f);
  return (unsigned short)((b + 0x7fffu + ((b >> 16) & 1u)) >> 16);
}
__device__ __forceinline__ unsigned pk2(float a, float b) {
  return (unsigned)pkb(a) | ((unsigned)pkb(b) << 16);
}

union U4S8 { uint4 u; s16x8 s; };

// ---------------- CSR build: counting-sort partition (no global atomics) ----

// K1: per-block per-bin histogram. bin = dst >> shift (<= 256 bins).
__global__ __launch_bounds__(256) void part_hist_k(
    const int* __restrict__ dst, int* __restrict__ histmat,
    int E, int nbins, int shift) {
  __shared__ int hist[256];
  const int t = threadIdx.x, blk = blockIdx.x;
  hist[t] = 0;
  __syncthreads();
  const int chunk = (E + PGB - 1) / PGB;
  const int e0 = blk * chunk, e1 = min(E, e0 + chunk);
  for (int i = e0 + t; i < e1; i += 256)
    atomicAdd(&hist[dst[i] >> shift], 1);
  __syncthreads();
  if (t < nbins) histmat[(size_t)t * PGB + blk] = hist[t];
}

// K2 (scan over nbins*PGB, bin-major) reuses scan_chunk/tops/add below.

__global__ void scan_chunk_k(const int* __restrict__ in, int* __restrict__ out,
                             int* __restrict__ sums, int n) {
  __shared__ int lds[256];
  int t = threadIdx.x;
  int base = blockIdx.x * 1024 + t * 4;
  int v0 = (base + 0 < n) ? in[base + 0] : 0;
  int v1 = (base + 1 < n) ? in[base + 1] : 0;
  int v2 = (base + 2 < n) ? in[base + 2] : 0;
  int v3 = (base + 3 < n) ? in[base + 3] : 0;
  int s = v0 + v1 + v2 + v3;
  lds[t] = s;
  __syncthreads();
  for (int off = 1; off < 256; off <<= 1) {
    int x = (t >= off) ? lds[t - off] : 0;
    __syncthreads();
    lds[t] += x;
    __syncthreads();
  }
  int excl = lds[t] - s;
  if (t == 255) sums[blockIdx.x] = lds[255];
  if (base + 0 < n) out[base + 0] = excl; excl += v0;
  if (base + 1 < n) out[base + 1] = excl; excl += v1;
  if (base + 2 < n) out[base + 2] = excl; excl += v2;
  if (base + 3 < n) out[base + 3] = excl;
}

__global__ void scan_tops_k(int* __restrict__ sums, int nb) {
  if (threadIdx.x == 0 && blockIdx.x == 0) {
    int run = 0;
    for (int i = 0; i < nb; ++i) { int x = sums[i]; sums[i] = run; run += x; }
  }
}

__global__ void scan_add_k(int* __restrict__ out, const int* __restrict__ sums, int n) {
  int i = blockIdx.x * 256 + threadIdx.x;
  if (i < n) out[i] += sums[i >> 10];
}

// K3: scatter edges into bin-grouped array, packed (dst_local<<17)|src.
__global__ __launch_bounds__(256) void part_scatter_k(
    const int* __restrict__ src, const int* __restrict__ dst,
    const int* __restrict__ histoff, unsigned* __restrict__ binned,
    int E, int nbins, int shift) {
  __shared__ int cur[256];
  const int t = threadIdx.x, blk = blockIdx.x;
  if (t < nbins) cur[t] = histoff[(size_t)t * PGB + blk];
  __syncthreads();
  const int chunk = (E + PGB - 1) / PGB;
  const int e0 = blk * chunk, e1 = min(E, e0 + chunk);
  const int mask = (1 << shift) - 1;
  for (int i = e0 + t; i < e1; i += 256) {
    int d = dst[i], s = src[i];
    int b = d >> shift;
    int p = atomicAdd(&cur[b], 1);   // LDS atomic
    binned[p] = ((unsigned)(d & mask) << 17) | (unsigned)s;
  }
}

// K4: one block per bin -> local count, local scan, write off/cnt, build csr.
__global__ __launch_bounds__(256) void csr_bin_k(
    const unsigned* __restrict__ binned, const int* __restrict__ histoff,
    int* __restrict__ csr, int* __restrict__ off, int* __restrict__ cnt,
    int E, int nbins, int shift, int N) {
  __shared__ int lcnt[512], lex[512], tmp[256];
  const int t = threadIdx.x, bin = blockIdx.x;
  const int bw = 1 << shift;
  const int e0 = histoff[(size_t)bin * PGB];
  const int e1 = (bin + 1 < nbins) ? histoff[(size_t)(bin + 1) * PGB] : E;
  lcnt[t] = 0; lcnt[t + 256] = 0;
  __syncthreads();
  for (int i = e0 + t; i < e1; i += 256)
    atomicAdd(&lcnt[binned[i] >> 17], 1);   // LDS atomic
  __syncthreads();
  // exclusive scan over 512 entries (two 256-halves)
  int a = lcnt[t], b = lcnt[t + 256];
  tmp[t] = a; __syncthreads();
  for (int o = 1; o < 256; o <<= 1) {
    int x = (t >= o) ? tmp[t - o] : 0;
    __syncthreads(); tmp[t] += x; __syncthreads();
  }
  int inclA = tmp[t], totA = tmp[255];
  __syncthreads();
  tmp[t] = b; __syncthreads();
  for (int o = 1; o < 256; o <<= 1) {
    int x = (t >= o) ? tmp[t - o] : 0;
    __syncthreads(); tmp[t] += x; __syncthreads();
  }
  int inclB = tmp[t];
  lex[t] = inclA - a;
  lex[t + 256] = totA + inclB - b;
  __syncthreads();
  const int based = bin << shift;
  const int nd = min(bw, N - based);
  for (int dl = t; dl < nd; dl += 256) {
    off[based + dl] = e0 + lex[dl];
    cnt[based + dl] = lcnt[dl];
  }
  __syncthreads();
  lcnt[t] = lex[t]; lcnt[t + 256] = lex[t + 256];
  __syncthreads();
  for (int i = e0 + t; i < e1; i += 256) {
    unsigned u = binned[i];
    int dl = (int)(u >> 17);
    int p = atomicAdd(&lcnt[dl], 1);   // LDS atomic
    csr[e0 + p] = (int)(u & 0x1FFFFu);
  }
}

__global__ void inv_k(const int* __restrict__ cnt, float* __restrict__ inv, int n) {
  int i = blockIdx.x * 256 + threadIdx.x;
  if (i < n) inv[i] = 1.0f / fmaxf((float)cnt[i], 1.0f);
}

// ---------------- conversions ----------------

__global__ void cvt_bf16_k(const float* __restrict__ in, unsigned short* __restrict__ out, int n4) {
  int i = blockIdx.x * 256 + threadIdx.x;
  if (i < n4) {
    float4 v = ((const float4*)in)[i];
    ushort4 o;
    o.x = pkb(v.x); o.y = pkb(v.y); o.z = pkb(v.z); o.w = pkb(v.w);
    ((ushort4*)out)[i] = o;
  }
}

__global__ void pack_wcat_k(const float* __restrict__ Wrel, const float* __restrict__ Wroot,
                            unsigned short* __restrict__ Wcat) {
  int idx = blockIdx.x * 256 + threadIdx.x;  // 32768
  int n = idx >> 8, k = idx & 255;
  float v = (k < 128) ? Wrel[(n << 7) + k] : Wroot[(n << 7) + k - 128];
  Wcat[idx] = pkb(v);
}

// ---------------- aggregation: one wave/dst, 16 rows in flight ----------------

__global__ __launch_bounds__(256) void agg_mean_b(
    const unsigned short* __restrict__ xsrc, const int* __restrict__ csr,
    const int* __restrict__ off, const int* __restrict__ cnt,
    const float* __restrict__ inv, unsigned short* __restrict__ mean, int ndst) {
  int wid = blockIdx.x * 4 + (threadIdx.x >> 6);
  int lane = threadIdx.x & 63;
  if (wid >= ndst) return;
  int o = off[wid], deg = cnt[wid];
  int q = lane >> 4, sl = lane & 15;
  float acc[8] = {0.f, 0.f, 0.f, 0.f, 0.f, 0.f, 0.f, 0.f};
  int sN[4];
#pragma unroll
  for (int j = 0; j < 4; ++j) {
    int e = j * 4 + q;
    sN[j] = (e < deg) ? csr[o + e] : -1;
  }
  for (int i = 0; i < deg; i += 16) {
    int cu[4];
#pragma unroll
    for (int j = 0; j < 4; ++j) {
      cu[j] = sN[j];
      int e = i + 16 + j * 4 + q;
      sN[j] = (e < deg) ? csr[o + e] : -1;
    }
    uint4 v[4];
#pragma unroll
    for (int j = 0; j < 4; ++j)
      if (cu[j] >= 0) v[j] = *(const uint4*)(xsrc + (size_t)cu[j] * 128 + sl * 8);
#pragma unroll
    for (int j = 0; j < 4; ++j) {
      if (cu[j] >= 0) {
        acc[0] += lo16(v[j].x); acc[1] += hi16(v[j].x);
        acc[2] += lo16(v[j].y); acc[3] += hi16(v[j].y);
        acc[4] += lo16(v[j].z); acc[5] += hi16(v[j].z);
        acc[6] += lo16(v[j].w); acc[7] += hi16(v[j].w);
      }
    }
  }
#pragma unroll
  for (int j = 0; j < 8; ++j) {
    acc[j] += __shfl_xor(acc[j], 16);
    acc[j] += __shfl_xor(acc[j], 32);
  }
  if (q == 0) {
    float iv = inv[wid];
    uint4 r;
    r.x = pk2(acc[0] * iv, acc[1] * iv);
    r.y = pk2(acc[2] * iv, acc[3] * iv);
    r.z = pk2(acc[4] * iv, acc[5] * iv);
    r.w = pk2(acc[6] * iv, acc[7] * iv);
    *(uint4*)(mean + (size_t)wid * 128 + sl * 8) = r;
  }
}

// ---------------- conv GEMM (MFMA, no LDS/barriers) ----------------

__global__ __launch_bounds__(256) void conv_mfma_k(
    const unsigned short* __restrict__ A1, const unsigned short* __restrict__ A2,
    const unsigned short* __restrict__ Wcat, const float* __restrict__ bias,
    unsigned short* __restrict__ out, int n, int relu) {
  const int t = threadIdx.x;
  const int l = t & 63, wv = t >> 6;
  const int row0 = blockIdx.x * 128 + wv * 32;
  const int g = l >> 4;           // k-granule 0..3
  f32x4 acc[2][8] = {};

  int rowa[2];
#pragma unroll
  for (int fr = 0; fr < 2; ++fr) {
    int r = row0 + fr * 16 + (l & 15);
    rowa[fr] = r < n ? r : n - 1;
  }

  for (int ch = 0; ch < 8; ++ch) {
    const unsigned short* __restrict__ Asrc = (ch < 4) ? A1 : A2;
    const int kb = (ch & 3) * 32;
    s16x8 av[2];
#pragma unroll
    for (int fr = 0; fr < 2; ++fr)
      av[fr] = *(const s16x8*)(Asrc + (size_t)rowa[fr] * 128 + kb + g * 8);
#pragma unroll
    for (int fc = 0; fc < 8; ++fc) {
      int col = fc * 16 + (l & 15);
      s16x8 bv = *(const s16x8*)(Wcat + (size_t)col * 256 + ch * 32 + g * 8);
#pragma unroll
      for (int fr = 0; fr < 2; ++fr)
        acc[fr][fc] = __builtin_amdgcn_mfma_f32_16x16x32_bf16(av[fr], bv, acc[fr][fc], 0, 0, 0);
    }
  }

#pragma unroll
  for (int fc = 0; fc < 8; ++fc) {
    int col = fc * 16 + (l & 15);
    float bb = bias[col];
#pragma unroll
    for (int fr = 0; fr < 2; ++fr) {
      int rbase = row0 + fr * 16 + g * 4;
#pragma unroll
      for (int reg = 0; reg < 4; ++reg) {
        int row = rbase + reg;
        if (row < n) {
          float v = acc[fr][fc][reg] + bb;
          if (relu) v = fmaxf(v, 0.f);
          out[(size_t)row * 128 + col] = pkb(v);
        }
      }
    }
  }
}

// ---------------- decoder (barrier-free) ----------------

__global__ __launch_bounds__(256) void dec_mfma_k(
    const unsigned short* __restrict__ xv, const unsigned short* __restrict__ xh,
    const int* __restrict__ lv, const int* __restrict__ lh,
    const unsigned short* __restrict__ W1b, const float* __restrict__ b1,
    const unsigned short* __restrict__ W2b, const float* __restrict__ b2,
    const float* __restrict__ Wp, const float* __restrict__ bp,
    float* __restrict__ out, int L) {
  __shared__ unsigned short h1s[64 * 132];
  const int t = threadIdx.x;
  const int l = t & 63, wv = t >> 6;
  const int g = l >> 4;
  const int row0 = blockIdx.x * 64 + wv * 16;

  int rowc = row0 + (l & 15);
  rowc = rowc < L ? rowc : L - 1;
  const int iv = lv[rowc], ih = lh[rowc];

  f32x4 acc[8] = {};
  for (int ch = 0; ch < 4; ++ch) {
    uint4 a4 = *(const uint4*)(xv + (size_t)iv * 128 + ch * 32 + g * 8);
    uint4 b4 = *(const uint4*)(xh + (size_t)ih * 128 + ch * 32 + g * 8);
    U4S8 e;
    e.u.x = pk2(lo16(a4.x) - lo16(b4.x), hi16(a4.x) - hi16(b4.x));
    e.u.y = pk2(lo16(a4.y) - lo16(b4.y), hi16(a4.y) - hi16(b4.y));
    e.u.z = pk2(lo16(a4.z) - lo16(b4.z), hi16(a4.z) - hi16(b4.z));
    e.u.w = pk2(lo16(a4.w) - lo16(b4.w), hi16(a4.w) - hi16(b4.w));
#pragma unroll
    for (int fc = 0; fc < 8; ++fc) {
      int col = fc * 16 + (l & 15);
      s16x8 bv = *(const s16x8*)(W1b + (size_t)col * 128 + ch * 32 + g * 8);
      acc[fc] = __builtin_amdgcn_mfma_f32_16x16x32_bf16(e.s, bv, acc[fc], 0, 0, 0);
    }
  }

#pragma unroll
  for (int fc = 0; fc < 8; ++fc) {
    int col = fc * 16 + (l & 15);
    float bb = b1[col];
#pragma unroll
    for (int reg = 0; reg < 4; ++reg) {
      int hr = wv * 16 + g * 4 + reg;
      h1s[hr * 132 + col] = pkb(fmaxf(acc[fc][reg] + bb, 0.f));
    }
  }

  f32x4 acc2[2] = {};
  for (int kc = 0; kc < 4; ++kc) {
    s16x8 av2 = *(const s16x8*)(h1s + (wv * 16 + (l & 15)) * 132 + kc * 32 + g * 8);
#pragma unroll
    for (int fc = 0; fc < 2; ++fc) {
      s16x8 bv2 = *(const s16x8*)(W2b + (size_t)(fc * 16 + (l & 15)) * 128 + kc * 32 + g * 8);
      acc2[fc] = __builtin_amdgcn_mfma_f32_16x16x32_bf16(av2, bv2, acc2[fc], 0, 0, 0);
    }
  }

  float p[4] = {0.f, 0.f, 0.f, 0.f};
#pragma unroll
  for (int fc = 0; fc < 2; ++fc) {
    int col = fc * 16 + (l & 15);
    float wp = Wp[col], bb = b2[col];
#pragma unroll
    for (int reg = 0; reg < 4; ++reg)
      p[reg] += fmaxf(acc2[fc][reg] + bb, 0.f) * wp;
  }
#pragma unroll
  for (int reg = 0; reg < 4; ++reg) {
    p[reg] += __shfl_xor(p[reg], 1);
    p[reg] += __shfl_xor(p[reg], 2);
    p[reg] += __shfl_xor(p[reg], 4);
    p[reg] += __shfl_xor(p[reg], 8);
  }
  if ((l & 15) == 0) {
    float bb = bp[0];
#pragma unroll
    for (int reg = 0; reg < 4; ++reg) {
      int row = row0 + g * 4 + reg;
      if (row < L) out[row] = p[reg] + bb;
    }
  }
}

// ---------------- host launcher ----------------

extern "C" void kernel_launch(void* const* d_in, const int* in_sizes, int n_in,
                              void* d_out, int out_size, void* d_ws, size_t ws_size,
                              hipStream_t stream) {
  const float* x_virus = (const float*)d_in[0];
  const float* x_host  = (const float*)d_in[1];
  const int* src_vh = (const int*)d_in[2];
  const int* dst_vh = (const int*)d_in[3];
  const int* src_hv = (const int*)d_in[4];
  const int* dst_hv = (const int*)d_in[5];
  const int* lbl_v  = (const int*)d_in[6];
  const int* lbl_h  = (const int*)d_in[7];
  const float* Wrel[4] = {(const float*)d_in[8],  (const float*)d_in[11],
                          (const float*)d_in[14], (const float*)d_in[17]};
  const float* Wroot[4] = {(const float*)d_in[10], (const float*)d_in[13],
                           (const float*)d_in[16], (const float*)d_in[19]};
  const float* bias_c[4] = {(const float*)d_in[9], (const float*)d_in[12],
                            (const float*)d_in[15], (const float*)d_in[18]};
  const float* W1 = (const float*)d_in[20];
  const float* b1 = (const float*)d_in[21];
  const float* W2 = (const float*)d_in[22];
  const float* b2 = (const float*)d_in[23];
  const float* Wp = (const float*)d_in[24];
  const float* bp = (const float*)d_in[25];

  const int NV = in_sizes[0] / D;
  const int NH = in_sizes[1] / D;
  const int E  = in_sizes[2];
  const int L  = in_sizes[6];

  // ---- workspace carve-up ----
  char* ws = (char*)d_ws;
  size_t o = 0;
  auto balloc = [&](size_t nb) { char* p = ws + o; o += (nb + 255) & ~(size_t)255; return p; };
  unsigned short* xvb   = (unsigned short*)balloc((size_t)NV * D * 2);
  unsigned short* xhb   = (unsigned short*)balloc((size_t)NH * D * 2);
  unsigned short* xv1b  = (unsigned short*)balloc((size_t)NV * D * 2);
  unsigned short* xv2b  = (unsigned short*)balloc((size_t)NV * D * 2);
  unsigned short* xh1b  = (unsigned short*)balloc((size_t)NH * D * 2);
  unsigned short* xh2b  = (unsigned short*)balloc((size_t)NH * D * 2);
  unsigned short* meanb = (unsigned short*)balloc((size_t)NV * D * 2);
  unsigned short* Wcat[4];
  for (int c = 0; c < 4; ++c) Wcat[c] = (unsigned short*)balloc(128 * 256 * 2);
  unsigned short* W1b = (unsigned short*)balloc(128 * 128 * 2);
  unsigned short* W2b = (unsigned short*)balloc(32 * 128 * 2);
  float* inv_h = (float*)balloc((size_t)NH * 4);
  float* inv_v = (float*)balloc((size_t)NV * 4);
  int* cnt_h = (int*)balloc((size_t)NH * 4);
  int* cnt_v = (int*)balloc((size_t)NV * 4);
  int* off_h = (int*)balloc((size_t)NH * 4);
  int* off_v = (int*)balloc((size_t)NV * 4);
  int* csr_h = (int*)balloc((size_t)E * 4);
  int* csr_v = (int*)balloc((size_t)E * 4);
  int* histmat = (int*)balloc((size_t)256 * PGB * 4);
  int* histoff = (int*)balloc((size_t)256 * PGB * 4);
  unsigned* binned = (unsigned*)balloc((size_t)E * 4);
  int* sums = (int*)balloc(256 * 4);

  auto cdiv = [](int a, int b) { return (a + b - 1) / b; };
  auto calc_shift = [](int n) { int s = 0; while ((1 << s) * 256 < n) ++s; return s; };

  // ---- CSR build, both sides (all atomics LDS-local) ----
  struct Side { const int* src; const int* dst; int N; int* csr; int* off; int* cnt; float* inv; };
  Side sides[2] = {
      {src_vh, dst_vh, NH, csr_h, off_h, cnt_h, inv_h},   // vh edges -> host dsts
      {src_hv, dst_hv, NV, csr_v, off_v, cnt_v, inv_v},   // hv edges -> virus dsts
  };
  for (int s = 0; s < 2; ++s) {
    const int N = sides[s].N;
    const int shift = calc_shift(N);
    const int nbins = cdiv(N, 1 << shift);
    const int nsc = nbins * PGB;
    part_hist_k<<<PGB, 256, 0, stream>>>(sides[s].dst, histmat, E, nbins, shift);
    scan_chunk_k<<<cdiv(nsc, 1024), 256, 0, stream>>>(histmat, histoff, sums, nsc);
    scan_tops_k<<<1, 64, 0, stream>>>(sums, cdiv(nsc, 1024));
    scan_add_k<<<cdiv(nsc, 256), 256, 0, stream>>>(histoff, sums, nsc);
    part_scatter_k<<<PGB, 256, 0, stream>>>(sides[s].src, sides[s].dst, histoff, binned, E, nbins, shift);
    csr_bin_k<<<nbins, 256, 0, stream>>>(binned, histoff, sides[s].csr, sides[s].off,
                                         sides[s].cnt, E, nbins, shift, N);
    inv_k<<<cdiv(N, 256), 256, 0, stream>>>(sides[s].cnt, sides[s].inv, N);
  }

  // conversions
  cvt_bf16_k<<<cdiv(NV * D / 4, 256), 256, 0, stream>>>(x_virus, xvb, NV * D / 4);
  cvt_bf16_k<<<cdiv(NH * D / 4, 256), 256, 0, stream>>>(x_host, xhb, NH * D / 4);
  for (int c = 0; c < 4; ++c)
    pack_wcat_k<<<128, 256, 0, stream>>>(Wrel[c], Wroot[c], Wcat[c]);
  cvt_bf16_k<<<cdiv(128 * 128 / 4, 256), 256, 0, stream>>>(W1, W1b, 128 * 128 / 4);
  cvt_bf16_k<<<cdiv(32 * 128 / 4, 256), 256, 0, stream>>>(W2, W2b, 32 * 128 / 4);

  // ---- layer 0 (relu) ----
  agg_mean_b<<<cdiv(NH, 4), 256, 0, stream>>>(xvb, csr_h, off_h, cnt_h, inv_h, meanb, NH);
  conv_mfma_k<<<cdiv(NH, 128), 256, 0, stream>>>(meanb, xhb, Wcat[0], bias_c[0], xh1b, NH, 1);
  agg_mean_b<<<cdiv(NV, 4), 256, 0, stream>>>(xhb, csr_v, off_v, cnt_v, inv_v, meanb, NV);
  conv_mfma_k<<<cdiv(NV, 128), 256, 0, stream>>>(meanb, xvb, Wcat[1], bias_c[1], xv1b, NV, 1);

  // ---- layer 1 (no relu) ----
  agg_mean_b<<<cdiv(NH, 4), 256, 0, stream>>>(xv1b, csr_h, off_h, cnt_h, inv_h, meanb, NH);
  conv_mfma_k<<<cdiv(NH, 128), 256, 0, stream>>>(meanb, xh1b, Wcat[2], bias_c[2], xh2b, NH, 0);
  agg_mean_b<<<cdiv(NV, 4), 256, 0, stream>>>(xh1b, csr_v, off_v, cnt_v, inv_v, meanb, NV);
  conv_mfma_k<<<cdiv(NV, 128), 256, 0, stream>>>(meanb, xv1b, Wcat[3], bias_c[3], xv2b, NV, 0);

  // ---- decoder ----
  dec_mfma_k<<<cdiv(L, 64), 256, 0, stream>>>(xv2b, xh2b, lbl_v, lbl_h, W1b, b1,
                                              W2b, b2, Wp, bp, (float*)d_out, L);
}

// Round 7
// 535.171 us; speedup vs baseline: 2.3430x; 1.0716x over previous
//
#include <hip/hip_runtime.h>

// GNN: 2-layer bipartite GraphConv + link decoder.
// Round 7: W1 folded into layer-1 conv weights (layer 1 has no relu) ->
// decoder gathers precomputed Pv/Ph and needs only stage-2 MFMA.
// Counting-sort CSR (R6), bf16 + fp32-accum MFMA everywhere.

#define D 128
#define PGB 256   // partition grid blocks

typedef float f32x4 __attribute__((ext_vector_type(4)));
typedef short s16x8 __attribute__((ext_vector_type(8)));

__device__ __forceinline__ float lo16(unsigned u) { return __uint_as_float(u << 16); }
__device__ __forceinline__ float hi16(unsigned u) { return __uint_as_float(u & 0xffff0000u); }
__device__ __forceinline__ unsigned short pkb(float f) {
  unsigned b = __float_as_uint(f);
  return (unsigned short)((b + 0x7fffu + ((b >> 16) & 1u)) >> 16);
}
__device__ __forceinline__ unsigned pk2(float a, float b) {
  return (unsigned)pkb(a) | ((unsigned)pkb(b) << 16);
}

union U4S8 { uint4 u; s16x8 s; };

// ---------------- CSR build: counting-sort partition (no global atomics) ----

__global__ __launch_bounds__(256) void part_hist_k(
    const int* __restrict__ dst, int* __restrict__ histmat,
    int E, int nbins, int shift) {
  __shared__ int hist[256];
  const int t = threadIdx.x, blk = blockIdx.x;
  hist[t] = 0;
  __syncthreads();
  const int chunk = (E + PGB - 1) / PGB;
  const int e0 = blk * chunk, e1 = min(E, e0 + chunk);
  for (int i = e0 + t; i < e1; i += 256)
    atomicAdd(&hist[dst[i] >> shift], 1);
  __syncthreads();
  if (t < nbins) histmat[(size_t)t * PGB + blk] = hist[t];
}

__global__ void scan_chunk_k(const int* __restrict__ in, int* __restrict__ out,
                             int* __restrict__ sums, int n) {
  __shared__ int lds[256];
  int t = threadIdx.x;
  int base = blockIdx.x * 1024 + t * 4;
  int v0 = (base + 0 < n) ? in[base + 0] : 0;
  int v1 = (base + 1 < n) ? in[base + 1] : 0;
  int v2 = (base + 2 < n) ? in[base + 2] : 0;
  int v3 = (base + 3 < n) ? in[base + 3] : 0;
  int s = v0 + v1 + v2 + v3;
  lds[t] = s;
  __syncthreads();
  for (int off = 1; off < 256; off <<= 1) {
    int x = (t >= off) ? lds[t - off] : 0;
    __syncthreads();
    lds[t] += x;
    __syncthreads();
  }
  int excl = lds[t] - s;
  if (t == 255) sums[blockIdx.x] = lds[255];
  if (base + 0 < n) out[base + 0] = excl; excl += v0;
  if (base + 1 < n) out[base + 1] = excl; excl += v1;
  if (base + 2 < n) out[base + 2] = excl; excl += v2;
  if (base + 3 < n) out[base + 3] = excl;
}

__global__ void scan_tops_k(int* __restrict__ sums, int nb) {
  if (threadIdx.x == 0 && blockIdx.x == 0) {
    int run = 0;
    for (int i = 0; i < nb; ++i) { int x = sums[i]; sums[i] = run; run += x; }
  }
}

__global__ void scan_add_k(int* __restrict__ out, const int* __restrict__ sums, int n) {
  int i = blockIdx.x * 256 + threadIdx.x;
  if (i < n) out[i] += sums[i >> 10];
}

__global__ __launch_bounds__(256) void part_scatter_k(
    const int* __restrict__ src, const int* __restrict__ dst,
    const int* __restrict__ histoff, unsigned* __restrict__ binned,
    int E, int nbins, int shift) {
  __shared__ int cur[256];
  const int t = threadIdx.x, blk = blockIdx.x;
  if (t < nbins) cur[t] = histoff[(size_t)t * PGB + blk];
  __syncthreads();
  const int chunk = (E + PGB - 1) / PGB;
  const int e0 = blk * chunk, e1 = min(E, e0 + chunk);
  const int mask = (1 << shift) - 1;
  for (int i = e0 + t; i < e1; i += 256) {
    int d = dst[i], s = src[i];
    int b = d >> shift;
    int p = atomicAdd(&cur[b], 1);   // LDS atomic
    binned[p] = ((unsigned)(d & mask) << 17) | (unsigned)s;
  }
}

__global__ __launch_bounds__(256) void csr_bin_k(
    const unsigned* __restrict__ binned, const int* __restrict__ histoff,
    int* __restrict__ csr, int* __restrict__ off, int* __restrict__ cnt,
    float* __restrict__ inv, int E, int nbins, int shift, int N) {
  __shared__ int lcnt[512], lex[512], tmp[256];
  const int t = threadIdx.x, bin = blockIdx.x;
  const int bw = 1 << shift;
  const int e0 = histoff[(size_t)bin * PGB];
  const int e1 = (bin + 1 < nbins) ? histoff[(size_t)(bin + 1) * PGB] : E;
  lcnt[t] = 0; lcnt[t + 256] = 0;
  __syncthreads();
  for (int i = e0 + t; i < e1; i += 256)
    atomicAdd(&lcnt[binned[i] >> 17], 1);   // LDS atomic
  __syncthreads();
  int a = lcnt[t], b = lcnt[t + 256];
  tmp[t] = a; __syncthreads();
  for (int o = 1; o < 256; o <<= 1) {
    int x = (t >= o) ? tmp[t - o] : 0;
    __syncthreads(); tmp[t] += x; __syncthreads();
  }
  int inclA = tmp[t], totA = tmp[255];
  __syncthreads();
  tmp[t] = b; __syncthreads();
  for (int o = 1; o < 256; o <<= 1) {
    int x = (t >= o) ? tmp[t - o] : 0;
    __syncthreads(); tmp[t] += x; __syncthreads();
  }
  int inclB = tmp[t];
  lex[t] = inclA - a;
  lex[t + 256] = totA + inclB - b;
  __syncthreads();
  const int based = bin << shift;
  const int nd = min(bw, N - based);
  for (int dl = t; dl < nd; dl += 256) {
    int c = lcnt[dl];
    off[based + dl] = e0 + lex[dl];
    cnt[based + dl] = c;
    inv[based + dl] = 1.0f / fmaxf((float)c, 1.0f);
  }
  __syncthreads();
  lcnt[t] = lex[t]; lcnt[t + 256] = lex[t + 256];
  __syncthreads();
  for (int i = e0 + t; i < e1; i += 256) {
    unsigned u = binned[i];
    int dl = (int)(u >> 17);
    int p = atomicAdd(&lcnt[dl], 1);   // LDS atomic
    csr[e0 + p] = (int)(u & 0x1FFFFu);
  }
}

// ---------------- conversions / weight prep ----------------

__global__ void cvt_bf16_k(const float* __restrict__ in, unsigned short* __restrict__ out, int n4) {
  int i = blockIdx.x * 256 + threadIdx.x;
  if (i < n4) {
    float4 v = ((const float4*)in)[i];
    ushort4 o;
    o.x = pkb(v.x); o.y = pkb(v.y); o.z = pkb(v.z); o.w = pkb(v.w);
    ((ushort4*)out)[i] = o;
  }
}

__global__ void pack_wcat_k(const float* __restrict__ Wrel, const float* __restrict__ Wroot,
                            unsigned short* __restrict__ Wcat) {
  int idx = blockIdx.x * 256 + threadIdx.x;  // 32768
  int n = idx >> 8, k = idx & 255;
  float v = (k < 128) ? Wrel[(n << 7) + k] : Wroot[(n << 7) + k - 128];
  Wcat[idx] = pkb(v);
}

// WcatF[i][kk] = sum_o W1[i][o] * (kk<128 ? Wrel[o][kk] : Wroot[o][kk-128]);
// biasF[i] = sum_o W1[i][o]*brel[o] (+ b1[i] if b1 != null)
__global__ __launch_bounds__(256) void fuse_w_k(
    const float* __restrict__ W1, const float* __restrict__ Wrel,
    const float* __restrict__ Wroot, const float* __restrict__ brel,
    const float* __restrict__ b1, unsigned short* __restrict__ Wf,
    float* __restrict__ biasF) {
  const int i = blockIdx.x;      // output channel 0..127
  const int kk = threadIdx.x;    // 0..255
  const float* __restrict__ Wsrc = (kk < 128) ? Wrel : Wroot;
  const int k = kk & 127;
  float s = 0.f;
  for (int o = 0; o < 128; ++o)
    s += W1[i * 128 + o] * Wsrc[o * 128 + k];
  Wf[i * 256 + kk] = pkb(s);
  if (kk == 0) {
    float sb = b1 ? b1[i] : 0.f;
    for (int o = 0; o < 128; ++o) sb += W1[i * 128 + o] * brel[o];
    biasF[i] = sb;
  }
}

// ---------------- aggregation: one wave/dst, 16 rows in flight ----------------

__global__ __launch_bounds__(256) void agg_mean_b(
    const unsigned short* __restrict__ xsrc, const int* __restrict__ csr,
    const int* __restrict__ off, const int* __restrict__ cnt,
    const float* __restrict__ inv, unsigned short* __restrict__ mean, int ndst) {
  int wid = blockIdx.x * 4 + (threadIdx.x >> 6);
  int lane = threadIdx.x & 63;
  if (wid >= ndst) return;
  int o = off[wid], deg = cnt[wid];
  int q = lane >> 4, sl = lane & 15;
  float acc[8] = {0.f, 0.f, 0.f, 0.f, 0.f, 0.f, 0.f, 0.f};
  int sN[4];
#pragma unroll
  for (int j = 0; j < 4; ++j) {
    int e = j * 4 + q;
    sN[j] = (e < deg) ? csr[o + e] : -1;
  }
  for (int i = 0; i < deg; i += 16) {
    int cu[4];
#pragma unroll
    for (int j = 0; j < 4; ++j) {
      cu[j] = sN[j];
      int e = i + 16 + j * 4 + q;
      sN[j] = (e < deg) ? csr[o + e] : -1;
    }
    uint4 v[4];
#pragma unroll
    for (int j = 0; j < 4; ++j)
      if (cu[j] >= 0) v[j] = *(const uint4*)(xsrc + (size_t)cu[j] * 128 + sl * 8);
#pragma unroll
    for (int j = 0; j < 4; ++j) {
      if (cu[j] >= 0) {
        acc[0] += lo16(v[j].x); acc[1] += hi16(v[j].x);
        acc[2] += lo16(v[j].y); acc[3] += hi16(v[j].y);
        acc[4] += lo16(v[j].z); acc[5] += hi16(v[j].z);
        acc[6] += lo16(v[j].w); acc[7] += hi16(v[j].w);
      }
    }
  }
#pragma unroll
  for (int j = 0; j < 8; ++j) {
    acc[j] += __shfl_xor(acc[j], 16);
    acc[j] += __shfl_xor(acc[j], 32);
  }
  if (q == 0) {
    float iv = inv[wid];
    uint4 r;
    r.x = pk2(acc[0] * iv, acc[1] * iv);
    r.y = pk2(acc[2] * iv, acc[3] * iv);
    r.z = pk2(acc[4] * iv, acc[5] * iv);
    r.w = pk2(acc[6] * iv, acc[7] * iv);
    *(uint4*)(mean + (size_t)wid * 128 + sl * 8) = r;
  }
}

// ---------------- conv GEMM (MFMA, no LDS/barriers) ----------------

__global__ __launch_bounds__(256) void conv_mfma_k(
    const unsigned short* __restrict__ A1, const unsigned short* __restrict__ A2,
    const unsigned short* __restrict__ Wcat, const float* __restrict__ bias,
    unsigned short* __restrict__ out, int n, int relu) {
  const int t = threadIdx.x;
  const int l = t & 63, wv = t >> 6;
  const int row0 = blockIdx.x * 128 + wv * 32;
  const int g = l >> 4;           // k-granule 0..3
  f32x4 acc[2][8] = {};

  int rowa[2];
#pragma unroll
  for (int fr = 0; fr < 2; ++fr) {
    int r = row0 + fr * 16 + (l & 15);
    rowa[fr] = r < n ? r : n - 1;
  }

  for (int ch = 0; ch < 8; ++ch) {
    const unsigned short* __restrict__ Asrc = (ch < 4) ? A1 : A2;
    const int kb = (ch & 3) * 32;
    s16x8 av[2];
#pragma unroll
    for (int fr = 0; fr < 2; ++fr)
      av[fr] = *(const s16x8*)(Asrc + (size_t)rowa[fr] * 128 + kb + g * 8);
#pragma unroll
    for (int fc = 0; fc < 8; ++fc) {
      int col = fc * 16 + (l & 15);
      s16x8 bv = *(const s16x8*)(Wcat + (size_t)col * 256 + ch * 32 + g * 8);
#pragma unroll
      for (int fr = 0; fr < 2; ++fr)
        acc[fr][fc] = __builtin_amdgcn_mfma_f32_16x16x32_bf16(av[fr], bv, acc[fr][fc], 0, 0, 0);
    }
  }

#pragma unroll
  for (int fc = 0; fc < 8; ++fc) {
    int col = fc * 16 + (l & 15);
    float bb = bias[col];
#pragma unroll
    for (int fr = 0; fr < 2; ++fr) {
      int rbase = row0 + fr * 16 + g * 4;
#pragma unroll
      for (int reg = 0; reg < 4; ++reg) {
        int row = rbase + reg;
        if (row < n) {
          float v = acc[fr][fc][reg] + bb;
          if (relu) v = fmaxf(v, 0.f);
          out[(size_t)row * 128 + col] = pkb(v);
        }
      }
    }
  }
}

// ---------------- decoder: h1 = relu(Pv[lv]-Ph[lh]); stage2 MFMA; dot ----------

__global__ __launch_bounds__(256) void dec2_k(
    const unsigned short* __restrict__ Pv, const unsigned short* __restrict__ Ph,
    const int* __restrict__ lv, const int* __restrict__ lh,
    const unsigned short* __restrict__ W2b, const float* __restrict__ b2,
    const float* __restrict__ Wp, const float* __restrict__ bp,
    float* __restrict__ out, int L) {
  const int t = threadIdx.x;
  const int l = t & 63, wv = t >> 6;
  const int g = l >> 4;
  const int row0 = blockIdx.x * 64 + wv * 16;

  int rowc = row0 + (l & 15);
  rowc = rowc < L ? rowc : L - 1;
  const int iv = lv[rowc], ih = lh[rowc];
  const unsigned short* __restrict__ pv = Pv + (size_t)iv * 128 + g * 8;
  const unsigned short* __restrict__ ph = Ph + (size_t)ih * 128 + g * 8;

  uint4 A[4], B[4];
#pragma unroll
  for (int ch = 0; ch < 4; ++ch) A[ch] = *(const uint4*)(pv + ch * 32);
#pragma unroll
  for (int ch = 0; ch < 4; ++ch) B[ch] = *(const uint4*)(ph + ch * 32);

  s16x8 e[4];
#pragma unroll
  for (int ch = 0; ch < 4; ++ch) {
    U4S8 u;
    u.u.x = pk2(fmaxf(lo16(A[ch].x) - lo16(B[ch].x), 0.f), fmaxf(hi16(A[ch].x) - hi16(B[ch].x), 0.f));
    u.u.y = pk2(fmaxf(lo16(A[ch].y) - lo16(B[ch].y), 0.f), fmaxf(hi16(A[ch].y) - hi16(B[ch].y), 0.f));
    u.u.z = pk2(fmaxf(lo16(A[ch].z) - lo16(B[ch].z), 0.f), fmaxf(hi16(A[ch].z) - hi16(B[ch].z), 0.f));
    u.u.w = pk2(fmaxf(lo16(A[ch].w) - lo16(B[ch].w), 0.f), fmaxf(hi16(A[ch].w) - hi16(B[ch].w), 0.f));
    e[ch] = u.s;
  }

  f32x4 acc2[2] = {};
#pragma unroll
  for (int kc = 0; kc < 4; ++kc) {
#pragma unroll
    for (int fc = 0; fc < 2; ++fc) {
      s16x8 bv = *(const s16x8*)(W2b + (size_t)(fc * 16 + (l & 15)) * 128 + kc * 32 + g * 8);
      acc2[fc] = __builtin_amdgcn_mfma_f32_16x16x32_bf16(e[kc], bv, acc2[fc], 0, 0, 0);
    }
  }

  float p[4] = {0.f, 0.f, 0.f, 0.f};
#pragma unroll
  for (int fc = 0; fc < 2; ++fc) {
    int col = fc * 16 + (l & 15);
    float wp = Wp[col], bb = b2[col];
#pragma unroll
    for (int reg = 0; reg < 4; ++reg)
      p[reg] += fmaxf(acc2[fc][reg] + bb, 0.f) * wp;
  }
#pragma unroll
  for (int reg = 0; reg < 4; ++reg) {
    p[reg] += __shfl_xor(p[reg], 1);
    p[reg] += __shfl_xor(p[reg], 2);
    p[reg] += __shfl_xor(p[reg], 4);
    p[reg] += __shfl_xor(p[reg], 8);
  }
  if ((l & 15) == 0) {
    float bb = bp[0];
#pragma unroll
    for (int reg = 0; reg < 4; ++reg) {
      int row = row0 + g * 4 + reg;
      if (row < L) out[row] = p[reg] + bb;
    }
  }
}

// ---------------- host launcher ----------------

extern "C" void kernel_launch(void* const* d_in, const int* in_sizes, int n_in,
                              void* d_out, int out_size, void* d_ws, size_t ws_size,
                              hipStream_t stream) {
  const float* x_virus = (const float*)d_in[0];
  const float* x_host  = (const float*)d_in[1];
  const int* src_vh = (const int*)d_in[2];
  const int* dst_vh = (const int*)d_in[3];
  const int* src_hv = (const int*)d_in[4];
  const int* dst_hv = (const int*)d_in[5];
  const int* lbl_v  = (const int*)d_in[6];
  const int* lbl_h  = (const int*)d_in[7];
  const float* Wrel[4] = {(const float*)d_in[8],  (const float*)d_in[11],
                          (const float*)d_in[14], (const float*)d_in[17]};
  const float* Wroot[4] = {(const float*)d_in[10], (const float*)d_in[13],
                           (const float*)d_in[16], (const float*)d_in[19]};
  const float* bias_c[4] = {(const float*)d_in[9], (const float*)d_in[12],
                            (const float*)d_in[15], (const float*)d_in[18]};
  const float* W1 = (const float*)d_in[20];
  const float* b1 = (const float*)d_in[21];
  const float* W2 = (const float*)d_in[22];
  const float* b2 = (const float*)d_in[23];
  const float* Wp = (const float*)d_in[24];
  const float* bp = (const float*)d_in[25];

  const int NV = in_sizes[0] / D;
  const int NH = in_sizes[1] / D;
  const int E  = in_sizes[2];
  const int L  = in_sizes[6];

  // ---- workspace carve-up ----
  char* ws = (char*)d_ws;
  size_t o = 0;
  auto balloc = [&](size_t nb) { char* p = ws + o; o += (nb + 255) & ~(size_t)255; return p; };
  unsigned short* xvb   = (unsigned short*)balloc((size_t)NV * D * 2);
  unsigned short* xhb   = (unsigned short*)balloc((size_t)NH * D * 2);
  unsigned short* xv1b  = (unsigned short*)balloc((size_t)NV * D * 2);
  unsigned short* Pvb   = (unsigned short*)balloc((size_t)NV * D * 2);
  unsigned short* xh1b  = (unsigned short*)balloc((size_t)NH * D * 2);
  unsigned short* Phb   = (unsigned short*)balloc((size_t)NH * D * 2);
  unsigned short* meanb = (unsigned short*)balloc((size_t)NV * D * 2);
  unsigned short* Wcat0 = (unsigned short*)balloc(128 * 256 * 2);
  unsigned short* Wcat1 = (unsigned short*)balloc(128 * 256 * 2);
  unsigned short* WcatFh = (unsigned short*)balloc(128 * 256 * 2);
  unsigned short* WcatFv = (unsigned short*)balloc(128 * 256 * 2);
  unsigned short* W2b = (unsigned short*)balloc(32 * 128 * 2);
  float* biasFh = (float*)balloc(128 * 4);
  float* biasFv = (float*)balloc(128 * 4);
  float* inv_h = (float*)balloc((size_t)NH * 4);
  float* inv_v = (float*)balloc((size_t)NV * 4);
  int* cnt_h = (int*)balloc((size_t)NH * 4);
  int* cnt_v = (int*)balloc((size_t)NV * 4);
  int* off_h = (int*)balloc((size_t)NH * 4);
  int* off_v = (int*)balloc((size_t)NV * 4);
  int* csr_h = (int*)balloc((size_t)E * 4);
  int* csr_v = (int*)balloc((size_t)E * 4);
  int* histmat = (int*)balloc((size_t)256 * PGB * 4);
  int* histoff = (int*)balloc((size_t)256 * PGB * 4);
  unsigned* binned = (unsigned*)balloc((size_t)E * 4);
  int* sums = (int*)balloc(256 * 4);

  auto cdiv = [](int a, int b) { return (a + b - 1) / b; };
  auto calc_shift = [](int n) { int s = 0; while ((1 << s) * 256 < n) ++s; return s; };

  // ---- CSR build, both sides (all atomics LDS-local) ----
  struct Side { const int* src; const int* dst; int N; int* csr; int* off; int* cnt; float* inv; };
  Side sides[2] = {
      {src_vh, dst_vh, NH, csr_h, off_h, cnt_h, inv_h},
      {src_hv, dst_hv, NV, csr_v, off_v, cnt_v, inv_v},
  };
  for (int s = 0; s < 2; ++s) {
    const int N = sides[s].N;
    const int shift = calc_shift(N);
    const int nbins = cdiv(N, 1 << shift);
    const int nsc = nbins * PGB;
    part_hist_k<<<PGB, 256, 0, stream>>>(sides[s].dst, histmat, E, nbins, shift);
    scan_chunk_k<<<cdiv(nsc, 1024), 256, 0, stream>>>(histmat, histoff, sums, nsc);
    scan_tops_k<<<1, 64, 0, stream>>>(sums, cdiv(nsc, 1024));
    scan_add_k<<<cdiv(nsc, 256), 256, 0, stream>>>(histoff, sums, nsc);
    part_scatter_k<<<PGB, 256, 0, stream>>>(sides[s].src, sides[s].dst, histoff, binned, E, nbins, shift);
    csr_bin_k<<<nbins, 256, 0, stream>>>(binned, histoff, sides[s].csr, sides[s].off,
                                         sides[s].cnt, sides[s].inv, E, nbins, shift, N);
  }

  // conversions + weight prep
  cvt_bf16_k<<<cdiv(NV * D / 4, 256), 256, 0, stream>>>(x_virus, xvb, NV * D / 4);
  cvt_bf16_k<<<cdiv(NH * D / 4, 256), 256, 0, stream>>>(x_host, xhb, NH * D / 4);
  pack_wcat_k<<<128, 256, 0, stream>>>(Wrel[0], Wroot[0], Wcat0);
  pack_wcat_k<<<128, 256, 0, stream>>>(Wrel[1], Wroot[1], Wcat1);
  // layer-1 weights fused with W1 (layer 1 has no relu): host side (vh), virus side (hv, +b1)
  fuse_w_k<<<128, 256, 0, stream>>>(W1, Wrel[2], Wroot[2], bias_c[2], nullptr, WcatFh, biasFh);
  fuse_w_k<<<128, 256, 0, stream>>>(W1, Wrel[3], Wroot[3], bias_c[3], b1, WcatFv, biasFv);
  cvt_bf16_k<<<cdiv(32 * 128 / 4, 256), 256, 0, stream>>>(W2, W2b, 32 * 128 / 4);

  // ---- layer 0 (relu) ----
  agg_mean_b<<<cdiv(NH, 4), 256, 0, stream>>>(xvb, csr_h, off_h, cnt_h, inv_h, meanb, NH);
  conv_mfma_k<<<cdiv(NH, 128), 256, 0, stream>>>(meanb, xhb, Wcat0, bias_c[0], xh1b, NH, 1);
  agg_mean_b<<<cdiv(NV, 4), 256, 0, stream>>>(xhb, csr_v, off_v, cnt_v, inv_v, meanb, NV);
  conv_mfma_k<<<cdiv(NV, 128), 256, 0, stream>>>(meanb, xvb, Wcat1, bias_c[1], xv1b, NV, 1);

  // ---- layer 1 fused with W1 (no relu): produces Pv/Ph pre-activations ----
  agg_mean_b<<<cdiv(NH, 4), 256, 0, stream>>>(xv1b, csr_h, off_h, cnt_h, inv_h, meanb, NH);
  conv_mfma_k<<<cdiv(NH, 128), 256, 0, stream>>>(meanb, xh1b, WcatFh, biasFh, Phb, NH, 0);
  agg_mean_b<<<cdiv(NV, 4), 256, 0, stream>>>(xh1b, csr_v, off_v, cnt_v, inv_v, meanb, NV);
  conv_mfma_k<<<cdiv(NV, 128), 256, 0, stream>>>(meanb, xv1b, WcatFv, biasFv, Pvb, NV, 0);

  // ---- decoder ----
  dec2_k<<<cdiv(L, 64), 256, 0, stream>>>(Pvb, Phb, lbl_v, lbl_h, W2b, b2,
                                          Wp, bp, (float*)d_out, L);
}